// Round 10
// baseline (1489.047 us; speedup 1.0000x reference)
//
#include <hip/hip_runtime.h>

// ---------------------------------------------------------------------------
// NeighborEmbedding — f16-MFMA grouped GEMMs + wave-per-center kNN +
// 4-wave DPP-reduce FPS (register-stashed outputs), multi-role fused launches:
//   K1 = fps1 | transpose | stem1   (all depend only on x)
//   K2 = fps2 | knn1 | stem2        (mutually independent)
// B=32, N=2048, SG1: s=512,K=32, 128->128, SG2: s=256,K=32, 256->256.
// ---------------------------------------------------------------------------

#define B_   32
#define N1_  2048
#define S1_  512
#define S2_  256
#define KG_  32
#define GPB  8

using f16 = _Float16;
typedef _Float16 f16x8 __attribute__((ext_vector_type(8)));
typedef _Float16 f16x4 __attribute__((ext_vector_type(4)));
typedef float    f32x4 __attribute__((ext_vector_type(4)));

// distance with FMA contraction OFF (FPS argmax / kNN selection are discrete)
__device__ __forceinline__ float dist3(float ax,float ay,float az,
                                       float bx,float by,float bz){
#pragma clang fp contract(off)
  float dx = ax - bx, dy = ay - by, dz = az - bz;
  return (dx*dx + dy*dy) + dz*dz;
}

// 64-lane max-reduce of a u64 key via DPP; lane 63 holds the max; readlane bcast.
__device__ __forceinline__ unsigned long long dpp_max_key(unsigned long long k){
  unsigned hi = (unsigned)(k >> 32), lo = (unsigned)k;
#define DPP_STEP(CTRL) { \
    unsigned h2 = (unsigned)__builtin_amdgcn_update_dpp((int)hi, (int)hi, CTRL, 0xf, 0xf, false); \
    unsigned l2 = (unsigned)__builtin_amdgcn_update_dpp((int)lo, (int)lo, CTRL, 0xf, 0xf, false); \
    if (h2 > hi || (h2 == hi && l2 > lo)){ hi = h2; lo = l2; } }
  DPP_STEP(0x111);  // row_shr:1
  DPP_STEP(0x112);  // row_shr:2
  DPP_STEP(0x114);  // row_shr:4
  DPP_STEP(0x118);  // row_shr:8
  DPP_STEP(0x142);  // row_bcast15
  DPP_STEP(0x143);  // row_bcast31
#undef DPP_STEP
  unsigned fh = (unsigned)__builtin_amdgcn_readlane((int)hi, 63);
  unsigned fl = (unsigned)__builtin_amdgcn_readlane((int)lo, 63);
  return ((unsigned long long)fh << 32) | fl;
}

struct FpsSmem {
  unsigned long long keyS[2][4];
  float cxS[2][4], cyS[2][4], czS[2][4];
};

// ---------------------------------------------------------------------------
// FPS device body: one 4-wave block per batch. NO global stores inside the
// step loop (round-9 finding: the tid0 idx/newxyz stores forced a vmcnt(0)
// drain at every __syncthreads — ~1300 cyc/step). Thread (s&255) stashes
// step s's result in registers; block writes everything once at the end.
// PACKED: pts[(b*NPTS+i)*3+d]. !PACKED: x[(b*3+d)*NPTS+i] (same values).
template<int NPTS, int SS, bool PACKED>
__device__ __forceinline__ void dev_fps(const float* __restrict__ pts,
                                        int* __restrict__ idx_out,
                                        float* __restrict__ newxyz,
                                        int b, FpsSmem& sm, int tid){
  constexpr int PL = NPTS/256;
  constexpr int ST = SS/256;
  const int lane = tid & 63, wid = tid >> 6;
  float px[PL], py[PL], pz[PL], d[PL];
  float cx, cy, cz;
  if (PACKED){
    const float* P = pts + (size_t)b*NPTS*3;
    #pragma unroll
    for (int t = 0; t < PL; ++t){
      int i = tid + 256*t;
      px[t] = P[i*3+0]; py[t] = P[i*3+1]; pz[t] = P[i*3+2];
      d[t] = 1e10f;
    }
    cx = P[0]; cy = P[1]; cz = P[2];
  } else {
    const float* X0 = pts + (size_t)(b*3+0)*NPTS;
    const float* X1 = pts + (size_t)(b*3+1)*NPTS;
    const float* X2 = pts + (size_t)(b*3+2)*NPTS;
    #pragma unroll
    for (int t = 0; t < PL; ++t){
      int i = tid + 256*t;
      px[t] = X0[i]; py[t] = X1[i]; pz[t] = X2[i];
      d[t] = 1e10f;
    }
    cx = X0[0]; cy = X1[0]; cz = X2[0];
  }
  int far = 0;
  int   far_st[ST];
  float cx_st[ST], cy_st[ST], cz_st[ST];
  for (int s = 0; s < SS; ++s){
    // stash this step's sample (result of previous fold / init) in registers
    if ((s & 255) == tid){
      int u = s >> 8;
      far_st[u] = far; cx_st[u] = cx; cy_st[u] = cy; cz_st[u] = cz;
    }
    unsigned long long lkey; float lx, ly, lz;
    {
      float nd = fminf(d[0], dist3(px[0],py[0],pz[0],cx,cy,cz));
      d[0] = nd;
      lkey = ((unsigned long long)__float_as_uint(nd) << 32) | (~(unsigned)tid);
      lx = px[0]; ly = py[0]; lz = pz[0];
    }
    #pragma unroll
    for (int t = 1; t < PL; ++t){
      float nd = fminf(d[t], dist3(px[t],py[t],pz[t],cx,cy,cz));
      d[t] = nd;
      unsigned long long k = ((unsigned long long)__float_as_uint(nd) << 32)
                           | (~(unsigned)(tid + 256*t));
      if (k > lkey){ lkey = k; lx = px[t]; ly = py[t]; lz = pz[t]; }
    }
    unsigned long long wkey = dpp_max_key(lkey);
    int wl = ((int)(~(unsigned)wkey)) & 63;
    float ox = __int_as_float(__builtin_amdgcn_readlane(__float_as_int(lx), wl));
    float oy = __int_as_float(__builtin_amdgcn_readlane(__float_as_int(ly), wl));
    float oz = __int_as_float(__builtin_amdgcn_readlane(__float_as_int(lz), wl));
    const int buf = s & 1;
    if (lane == 0){
      sm.keyS[buf][wid] = wkey;
      sm.cxS[buf][wid] = ox; sm.cyS[buf][wid] = oy; sm.czS[buf][wid] = oz;
    }
    __syncthreads();
    unsigned long long gk = sm.keyS[buf][0];
    float gx = sm.cxS[buf][0], gy = sm.cyS[buf][0], gz = sm.czS[buf][0];
    #pragma unroll
    for (int w = 1; w < 4; ++w){
      unsigned long long k = sm.keyS[buf][w];
      if (k > gk){ gk = k; gx = sm.cxS[buf][w]; gy = sm.cyS[buf][w]; gz = sm.czS[buf][w]; }
    }
    far = (int)(~(unsigned)gk);
    cx = gx; cy = gy; cz = gz;
  }
  // single writeback of all samples
  #pragma unroll
  for (int u = 0; u < ST; ++u){
    int s = u*256 + tid;
    idx_out[b*SS + s] = far_st[u];
    newxyz[(b*SS+s)*3+0] = cx_st[u];
    newxyz[(b*SS+s)*3+1] = cy_st[u];
    newxyz[(b*SS+s)*3+2] = cz_st[u];
  }
}

// ---------------------------------------------------------------------------
// kNN device body: one WAVE per center, register-resident, barrier-free.
template<int NPTS>
__device__ __forceinline__ void dev_knn(const float* __restrict__ pts,
                                        const float* __restrict__ ctr,
                                        int S, int* __restrict__ knn,
                                        int gblk, int tid){
  constexpr int PL = NPTS/64;
  const int lane = tid & 63;
  const int g = gblk*4 + (tid >> 6);
  const int b = g / S;
  const float cx = ctr[g*3+0], cy = ctr[g*3+1], cz = ctr[g*3+2];
  const float* P = pts + (size_t)b*NPTS*3;
  float d[PL];
  #pragma unroll
  for (int t = 0; t < PL; ++t){
    int i = lane + 64*t;
    d[t] = dist3(cx, cy, cz, P[i*3+0], P[i*3+1], P[i*3+2]);
  }
  for (int k = 0; k < KG_; ++k){
    float bv = d[0]; int bt = 0;
    #pragma unroll
    for (int t = 1; t < PL; ++t)
      if (d[t] < bv){ bv = d[t]; bt = t; }
    int bi = lane + 64*bt;
    #pragma unroll
    for (int off = 1; off < 64; off <<= 1){
      float ov = __shfl_xor(bv, off);
      int   oi = __shfl_xor(bi, off);
      if (ov < bv || (ov == bv && oi < bi)){ bv = ov; bi = oi; }
    }
    if (lane == k) knn[g*KG_ + k] = bi;
    if ((bi & 63) == lane){
      const int wt = bi >> 6;
      #pragma unroll
      for (int t = 0; t < PL; ++t)
        if (t == wt) d[t] = 3.0e38f;
    }
  }
}

template<int NPTS>
__global__ __launch_bounds__(256) void knnw_k(const float* __restrict__ pts,
                                              const float* __restrict__ ctr,
                                              int S, int* __restrict__ knn){
  dev_knn<NPTS>(pts, ctr, S, knn, blockIdx.x, threadIdx.x);
}

// ---------------------------------------------------------------------------
// K1 = fps1 | transpose | stem1 (all read only x). Blocks:
// [0,32): fps1, [32,800): transpose (768), [800,1824): stem1 (1024).
union K1Smem {
  FpsSmem fps;
  float red[64][5];
};
__global__ __launch_bounds__(256) void k1_k(const float* __restrict__ x,
                                            int* __restrict__ idx1,
                                            float* __restrict__ nx1,
                                            float* __restrict__ xyzb,
                                            const float* __restrict__ w1,
                                            float* __restrict__ ssum,
                                            float* __restrict__ ssq){
  __shared__ K1Smem sm;
  const int blk = blockIdx.x, tid = threadIdx.x;
  if (blk < B_){
    dev_fps<N1_, S1_, false>(x, idx1, nx1, blk, sm.fps, tid);
  } else if (blk < B_ + 768){
    int e = (blk - B_)*256 + tid;           // < B*N*3
    int d = e % 3; int n = (e/3) % N1_; int b = e / (3*N1_);
    xyzb[e] = x[(b*3 + d)*N1_ + n];
  } else {
    // stem1 stats: 64 rows/block, read x strided (same values as xyz rows)
    const int c  = tid & 63;
    const int sl = tid >> 6;
    const float wx = w1[c*3+0], wy = w1[c*3+1], wz = w1[c*3+2];
    const int base = (blk - (B_+768))*64 + sl*16;
    float ls = 0.f, lq = 0.f;
    for (int r = 0; r < 16; ++r){
      int m = base + r;
      int b = m >> 11, n = m & 2047;
      float xv = x[(b*3+0)*N1_ + n];
      float yv = x[(b*3+1)*N1_ + n];
      float zv = x[(b*3+2)*N1_ + n];
      float h = xv*wx + yv*wy + zv*wz;
      ls += h; lq += h*h;
    }
    sm.red[c][sl] = ls; __syncthreads();
    if (sl == 0) atomicAdd(&ssum[c], sm.red[c][0]+sm.red[c][1]+sm.red[c][2]+sm.red[c][3]);
    __syncthreads();
    sm.red[c][sl] = lq; __syncthreads();
    if (sl == 0) atomicAdd(&ssq[c], sm.red[c][0]+sm.red[c][1]+sm.red[c][2]+sm.red[c][3]);
  }
}

// ---------------------------------------------------------------------------
// K2 = fps2 | knn1 | stem2. Blocks:
// [0,32): fps2, [32,4128): knn1 (4096), [4128,5152): stem2 (1024).
union K2Smem {
  FpsSmem fps;
  struct { float As[32][68]; float Ws[32][68]; float red[64][17]; } s2;
};
__global__ __launch_bounds__(256) void k2_k(const float* __restrict__ x,
                                            const float* __restrict__ xyzb,
                                            const float* __restrict__ nx1,
                                            int* __restrict__ idx2,
                                            float* __restrict__ nx2,
                                            int* __restrict__ knn1,
                                            const float* __restrict__ w1,
                                            const float* __restrict__ s0,
                                            const float* __restrict__ b0,
                                            const float* __restrict__ w2,
                                            float* __restrict__ hout,
                                            float* __restrict__ ssum,
                                            float* __restrict__ ssq){
  __shared__ K2Smem sm;
  const int blk = blockIdx.x, tid = threadIdx.x;
  if (blk < B_){
    dev_fps<S1_, S2_, true>(nx1, idx2, nx2, blk, sm.fps, tid);
  } else if (blk < B_ + 4096){
    dev_knn<N1_>(xyzb, nx1, S1_, knn1, blk - B_, tid);
  } else {
    // stem2: 64x64 tile GEMM, recomputes layer1 from x on the fly
    const int m0 = (blk - (B_+4096)) * 64;
    const int lrow = tid >> 3;
    const int lk   = (tid & 7) * 4;
    const int tx = tid & 15, ty = tid >> 4;
    float acc[4][4];
    #pragma unroll
    for (int i=0;i<4;++i)
      #pragma unroll
      for (int j=0;j<4;++j) acc[i][j]=0.f;

    for (int k0 = 0; k0 < 64; k0 += 32){
      __syncthreads();
      #pragma unroll
      for (int p = 0; p < 2; ++p){
        int m = m0 + lrow + p*32;
        int b = m >> 11, n = m & 2047;
        float x0 = x[(b*3+0)*N1_ + n];
        float x1 = x[(b*3+1)*N1_ + n];
        float x2 = x[(b*3+2)*N1_ + n];
        #pragma unroll
        for (int j = 0; j < 4; ++j){
          int k = k0 + lk + j;
          float h = x0*w1[k*3+0] + x1*w1[k*3+1] + x2*w1[k*3+2];
          sm.s2.As[lk+j][lrow+p*32] = fmaxf(h*s0[k] + b0[k], 0.f);
        }
      }
      {
        const int cl = tid >> 2, kp = (tid & 3)*8;
        const float* wr = w2 + cl*64 + k0 + kp;
        #pragma unroll
        for (int q = 0; q < 2; ++q){
          float4 w = *reinterpret_cast<const float4*>(wr + q*4);
          sm.s2.Ws[kp+q*4+0][cl] = w.x; sm.s2.Ws[kp+q*4+1][cl] = w.y;
          sm.s2.Ws[kp+q*4+2][cl] = w.z; sm.s2.Ws[kp+q*4+3][cl] = w.w;
        }
      }
      __syncthreads();
      #pragma unroll
      for (int kk = 0; kk < 32; ++kk){
        float4 av = *reinterpret_cast<const float4*>(&sm.s2.As[kk][ty*4]);
        float4 wv = *reinterpret_cast<const float4*>(&sm.s2.Ws[kk][tx*4]);
        acc[0][0]+=av.x*wv.x; acc[0][1]+=av.x*wv.y; acc[0][2]+=av.x*wv.z; acc[0][3]+=av.x*wv.w;
        acc[1][0]+=av.y*wv.x; acc[1][1]+=av.y*wv.y; acc[1][2]+=av.y*wv.z; acc[1][3]+=av.y*wv.w;
        acc[2][0]+=av.z*wv.x; acc[2][1]+=av.z*wv.y; acc[2][2]+=av.z*wv.z; acc[2][3]+=av.z*wv.w;
        acc[3][0]+=av.w*wv.x; acc[3][1]+=av.w*wv.y; acc[3][2]+=av.w*wv.z; acc[3][3]+=av.w*wv.w;
      }
    }
    #pragma unroll
    for (int r = 0; r < 4; ++r){
      float4 o; o.x=acc[r][0]; o.y=acc[r][1]; o.z=acc[r][2]; o.w=acc[r][3];
      *reinterpret_cast<float4*>(hout + (size_t)(m0 + ty*4 + r)*64 + tx*4) = o;
    }
    __syncthreads();
    #pragma unroll
    for (int j = 0; j < 4; ++j)
      sm.s2.red[tx*4+j][ty] = acc[0][j]+acc[1][j]+acc[2][j]+acc[3][j];
    __syncthreads();
    if (tid < 64){
      float s = 0.f;
      #pragma unroll
      for (int t = 0; t < 16; ++t) s += sm.s2.red[tid][t];
      atomicAdd(&ssum[tid], s);
    }
    __syncthreads();
    #pragma unroll
    for (int j = 0; j < 4; ++j)
      sm.s2.red[tx*4+j][ty] = acc[0][j]*acc[0][j]+acc[1][j]*acc[1][j]
                            + acc[2][j]*acc[2][j]+acc[3][j]*acc[3][j];
    __syncthreads();
    if (tid < 64){
      float s = 0.f;
      #pragma unroll
      for (int t = 0; t < 16; ++t) s += sm.s2.red[tid][t];
      atomicAdd(&ssq[tid], s);
    }
  }
}

// ---------------------------------------------------------------------------
// pack fp32 weight rows into f16 B-fragment order
__global__ __launch_bounds__(256) void pack_w_k(const float* __restrict__ W,
                                                f16* __restrict__ out,
                                                int C, int Kfull, int koff,
                                                int total){
  int e = blockIdx.x*256 + threadIdx.x;
  if (e >= total) return;
  int lane = e & 63, tile = e >> 6;
  int ntiles = C/16;
  int nt = tile % ntiles, kt = tile / ntiles;
  int n = nt*16 + (lane & 15);
  int k0 = kt*32 + (lane >> 4)*8;
  const float* src = W + (size_t)n*Kfull + koff + k0;
  f16* dst = out + (size_t)e*8;
  #pragma unroll
  for (int j = 0; j < 8; ++j) dst[j] = (f16)src[j];
}

__global__ void finalize_bn_k(const float* __restrict__ ssum, const float* __restrict__ ssq,
                              const float* __restrict__ g,   const float* __restrict__ b,
                              float* __restrict__ scale, float* __restrict__ bias,
                              int C, float count){
  int c = threadIdx.x;
  if (c < C){
    double m = (double)ssum[c] / (double)count;
    double v = (double)ssq[c] / (double)count - m*m;
    if (v < 0.0) v = 0.0;
    float sc = g[c] * (float)(1.0 / sqrt(v + 1e-5));
    scale[c] = sc;
    bias[c]  = b[c] - (float)m * sc;
  }
}

__global__ __launch_bounds__(256) void bnrelu_k(const float* __restrict__ h,
                                                const float* __restrict__ sc,
                                                const float* __restrict__ bs,
                                                float* __restrict__ out, int total, int C){
  int e = blockIdx.x*256 + threadIdx.x;
  if (e < total){
    int c = e % C;
    out[e] = fmaxf(h[e]*sc[c] + bs[c], 0.f);
  }
}

__global__ __launch_bounds__(256) void gather_rows_k(const float* __restrict__ src,
                                                     const int* __restrict__ idx,
                                                     float* __restrict__ dst,
                                                     int total, int Dc, int Ssamp, int Npts){
  int e = blockIdx.x*256 + threadIdx.x;
  if (e < total){
    int g = e / Dc, c = e - g*Dc;
    int b = g / Ssamp;
    dst[e] = src[((size_t)(b*Npts + idx[g]))*Dc + c];
  }
}

// ---------------------------------------------------------------------------
// Fused SG-stage kernel, f16 MFMA (mfma_f32_16x16x32_f16). See round-4 notes.
template<int DIN, int PASS>
__global__ __launch_bounds__(256) void sgm_k(
    const float* __restrict__ f,   // [B*Npts, DIN]
    const float* __restrict__ cf,  // [B*S, DIN]
    const int* __restrict__ knn,
    const float* __restrict__ W1full,  // fp32 [C][2*DIN] (center half)
    const f16* __restrict__ W1p,       // packed rel half, K=DIN
    const f16* __restrict__ W2p,       // packed, K=C (PASS 1)
    const float* __restrict__ s1, const float* __restrict__ b1,
    float* __restrict__ ssum, float* __restrict__ ssq,
    float* __restrict__ gmx, float* __restrict__ gmn,
    int Npts, int S)
{
  constexpr int C   = 2*DIN;
  constexpr int NT  = C/16;     // n-tiles
  constexpr int KT1 = DIN/32;   // k-tiles layer1
  constexpr int KT2 = C/32;     // k-tiles layer2
  constexpr int NTW = NT/4;     // n-tiles per wave
  constexpr int RP  = DIN + 8;  // rel row pitch (halfs)
  constexpr int HP  = C + 8;    // hT row pitch (halfs)

  __shared__ f16 relS[32*RP];
  __shared__ float hcS[C];
  __shared__ float csS[DIN];
  __shared__ f16 hTS[PASS ? 32*HP : 8];

  const int tid = threadIdx.x;
  const int lane = tid & 63, wid = tid >> 6;
  const int col = lane & 15, quad = lane >> 4;

  float sAcc[NTW], qAcc[NTW];
  #pragma unroll
  for (int t = 0; t < NTW; ++t){ sAcc[t] = 0.f; qAcc[t] = 0.f; }

  for (int gi = 0; gi < GPB; ++gi){
    const int g = blockIdx.x*GPB + gi;
    const int b = g / S;
    __syncthreads();
    // ---- stage rel (f16) + center row ----
    {
      const int r = tid >> 3, part = tid & 7;
      const int j = knn[g*KG_ + r];
      const float* fr = f + (size_t)(b*Npts + j)*DIN + part*(DIN/8);
      const float* cr = cf + (size_t)g*DIN + part*(DIN/8);
      f16* dst = relS + r*RP + part*(DIN/8);
      #pragma unroll
      for (int q = 0; q < DIN/32; ++q){
        float4 fv = *reinterpret_cast<const float4*>(fr + q*4);
        float4 cv = *reinterpret_cast<const float4*>(cr + q*4);
        f16x4 hv;
        hv.x = (f16)(fv.x - cv.x); hv.y = (f16)(fv.y - cv.y);
        hv.z = (f16)(fv.z - cv.z); hv.w = (f16)(fv.w - cv.w);
        *reinterpret_cast<f16x4*>(dst + q*4) = hv;
      }
      if (tid < DIN) csS[tid] = cf[(size_t)g*DIN + tid];
    }
    __syncthreads();
    // ---- rank-1 center contribution (exact fp32) ----
    if (tid < C){
      const float* wr = W1full + (size_t)tid*C + DIN;
      float s = 0.f;
      for (int k = 0; k < DIN; k += 4){
        float4 w = *reinterpret_cast<const float4*>(wr + k);
        s += csS[k]*w.x + csS[k+1]*w.y + csS[k+2]*w.z + csS[k+3]*w.w;
      }
      hcS[tid] = s;
    }
    __syncthreads();

    // ---- layer1 A-frags ----
    f16x8 a1[2][KT1];
    #pragma unroll
    for (int mt = 0; mt < 2; ++mt)
      #pragma unroll
      for (int kt = 0; kt < KT1; ++kt)
        a1[mt][kt] = *reinterpret_cast<const f16x8*>(relS + (mt*16+col)*RP + kt*32 + quad*8);

    if (PASS == 0){
      #pragma unroll
      for (int t = 0; t < NTW; ++t){
        const int nt = wid*NTW + t;
        const float hc = hcS[nt*16 + col];
        f32x4 acc0 = {hc,hc,hc,hc}, acc1 = {hc,hc,hc,hc};
        #pragma unroll
        for (int kt = 0; kt < KT1; ++kt){
          f16x8 bf = *reinterpret_cast<const f16x8*>(W1p + ((size_t)(kt*NT + nt)*64 + lane)*8);
          acc0 = __builtin_amdgcn_mfma_f32_16x16x32_f16(a1[0][kt], bf, acc0, 0, 0, 0);
          acc1 = __builtin_amdgcn_mfma_f32_16x16x32_f16(a1[1][kt], bf, acc1, 0, 0, 0);
        }
        float s = acc0[0]+acc0[1]+acc0[2]+acc0[3] + acc1[0]+acc1[1]+acc1[2]+acc1[3];
        float q = acc0[0]*acc0[0]+acc0[1]*acc0[1]+acc0[2]*acc0[2]+acc0[3]*acc0[3]
                + acc1[0]*acc1[0]+acc1[1]*acc1[1]+acc1[2]*acc1[2]+acc1[3]*acc1[3];
        s += __shfl_xor(s, 16); s += __shfl_xor(s, 32);
        q += __shfl_xor(q, 16); q += __shfl_xor(q, 32);
        sAcc[t] += s; qAcc[t] += q;
      }
    } else {
      #pragma unroll
      for (int t = 0; t < NTW; ++t){
        const int nt = wid*NTW + t;
        const float hc = hcS[nt*16 + col];
        f32x4 acc0 = {hc,hc,hc,hc}, acc1 = {hc,hc,hc,hc};
        #pragma unroll
        for (int kt = 0; kt < KT1; ++kt){
          f16x8 bf = *reinterpret_cast<const f16x8*>(W1p + ((size_t)(kt*NT + nt)*64 + lane)*8);
          acc0 = __builtin_amdgcn_mfma_f32_16x16x32_f16(a1[0][kt], bf, acc0, 0, 0, 0);
          acc1 = __builtin_amdgcn_mfma_f32_16x16x32_f16(a1[1][kt], bf, acc1, 0, 0, 0);
        }
        const float sc = s1[nt*16+col], bs = b1[nt*16+col];
        #pragma unroll
        for (int r = 0; r < 4; ++r){
          hTS[(quad*4+r)*HP + nt*16+col]    = (f16)fmaxf(acc0[r]*sc + bs, 0.f);
          hTS[(16+quad*4+r)*HP + nt*16+col] = (f16)fmaxf(acc1[r]*sc + bs, 0.f);
        }
      }
      __syncthreads();   // hT complete (all waves)
      f16x8 a2[2][KT2];
      #pragma unroll
      for (int mt = 0; mt < 2; ++mt)
        #pragma unroll
        for (int kt = 0; kt < KT2; ++kt)
          a2[mt][kt] = *reinterpret_cast<const f16x8*>(hTS + (mt*16+col)*HP + kt*32 + quad*8);
      #pragma unroll
      for (int t = 0; t < NTW; ++t){
        const int nt = wid*NTW + t;
        f32x4 acc0 = {0.f,0.f,0.f,0.f}, acc1 = {0.f,0.f,0.f,0.f};
        #pragma unroll
        for (int kt = 0; kt < KT2; ++kt){
          f16x8 bf = *reinterpret_cast<const f16x8*>(W2p + ((size_t)(kt*NT + nt)*64 + lane)*8);
          acc0 = __builtin_amdgcn_mfma_f32_16x16x32_f16(a2[0][kt], bf, acc0, 0, 0, 0);
          acc1 = __builtin_amdgcn_mfma_f32_16x16x32_f16(a2[1][kt], bf, acc1, 0, 0, 0);
        }
        float s = acc0[0]+acc0[1]+acc0[2]+acc0[3] + acc1[0]+acc1[1]+acc1[2]+acc1[3];
        float q = acc0[0]*acc0[0]+acc0[1]*acc0[1]+acc0[2]*acc0[2]+acc0[3]*acc0[3]
                + acc1[0]*acc1[0]+acc1[1]*acc1[1]+acc1[2]*acc1[2]+acc1[3]*acc1[3];
        float mx = fmaxf(fmaxf(fmaxf(acc0[0],acc0[1]), fmaxf(acc0[2],acc0[3])),
                         fmaxf(fmaxf(acc1[0],acc1[1]), fmaxf(acc1[2],acc1[3])));
        float mn = fminf(fminf(fminf(acc0[0],acc0[1]), fminf(acc0[2],acc0[3])),
                         fminf(fminf(acc1[0],acc1[1]), fminf(acc1[2],acc1[3])));
        s += __shfl_xor(s, 16); s += __shfl_xor(s, 32);
        q += __shfl_xor(q, 16); q += __shfl_xor(q, 32);
        mx = fmaxf(mx, __shfl_xor(mx, 16)); mx = fmaxf(mx, __shfl_xor(mx, 32));
        mn = fminf(mn, __shfl_xor(mn, 16)); mn = fminf(mn, __shfl_xor(mn, 32));
        sAcc[t] += s; qAcc[t] += q;
        if (quad == 0){
          gmx[(size_t)g*C + nt*16 + col] = mx;
          gmn[(size_t)g*C + nt*16 + col] = mn;
        }
      }
    }
  } // group loop

  #pragma unroll
  for (int t = 0; t < NTW; ++t){
    const int nt = wid*NTW + t;
    if (quad == 0){
      atomicAdd(&ssum[nt*16 + col], sAcc[t]);
      atomicAdd(&ssq [nt*16 + col], qAcc[t]);
    }
  }
}

// combine: out[g][c] = relu(scale * (scale>=0 ? max : min) + bias)
__global__ __launch_bounds__(256) void combine_k(const float* __restrict__ mx,
                                                 const float* __restrict__ mn,
                                                 const float* __restrict__ sc,
                                                 const float* __restrict__ bs,
                                                 float* __restrict__ out, int total, int C){
  int e = blockIdx.x*256 + threadIdx.x;
  if (e < total){
    int c = e % C;
    float s = sc[c];
    float v = (s >= 0.f) ? mx[e] : mn[e];
    out[e] = fmaxf(s*v + bs[c], 0.f);
  }
}

// final: out[b][c][s] from group-major [b*S2+s][c]
__global__ __launch_bounds__(256) void final_out_k(const float* __restrict__ mx,
                                                   const float* __restrict__ mn,
                                                   const float* __restrict__ sc,
                                                   const float* __restrict__ bs,
                                                   float* __restrict__ out){
  int e = blockIdx.x*256 + threadIdx.x;     // < 32*256*256
  int s = e & 255;
  int c = (e >> 8) & 255;
  int b = e >> 16;
  int idx = ((b << 8) + s)*256 + c;
  float scv = sc[c];
  float v = (scv >= 0.f) ? mx[idx] : mn[idx];
  out[e] = fmaxf(scv*v + bs[c], 0.f);
}

// ---------------------------------------------------------------------------
extern "C" void kernel_launch(void* const* d_in, const int* in_sizes, int n_in,
                              void* d_out, int out_size, void* d_ws, size_t ws_size,
                              hipStream_t stream)
{
  const float* x      = (const float*)d_in[0];
  const float* w1     = (const float*)d_in[1];
  const float* g1     = (const float*)d_in[2];
  const float* b1     = (const float*)d_in[3];
  const float* w2     = (const float*)d_in[4];
  const float* g2     = (const float*)d_in[5];
  const float* b2     = (const float*)d_in[6];
  const float* sg1w1  = (const float*)d_in[7];
  const float* sg1g1  = (const float*)d_in[8];
  const float* sg1b1  = (const float*)d_in[9];
  const float* sg1w2  = (const float*)d_in[10];
  const float* sg1g2  = (const float*)d_in[11];
  const float* sg1b2  = (const float*)d_in[12];
  const float* sg2w1  = (const float*)d_in[13];
  const float* sg2g1  = (const float*)d_in[14];
  const float* sg2b1  = (const float*)d_in[15];
  const float* sg2w2  = (const float*)d_in[16];
  const float* sg2g2  = (const float*)d_in[17];
  const float* sg2b2  = (const float*)d_in[18];

  float* ws = (float*)d_ws;
  size_t off = 0;
  auto alloc = [&](size_t n){ float* p = ws + off; off += (n + 63) & ~(size_t)63; return p; };

  float* xyzb = alloc((size_t)B_*N1_*3);
  float* fbuf = alloc((size_t)B_*N1_*64);       // 16 MB
  float* f1   = alloc((size_t)B_*S1_*128);      // 8 MB
  float* cf   = alloc((size_t)B_*S1_*64);       // 4 MB (cf1; reused as cf2)
  float* nx1  = alloc((size_t)B_*S1_*3);
  float* nx2  = alloc((size_t)B_*S2_*3);
  float* stats= alloc(6*512);
  float* sb   = alloc(6*512);
  int* idx1   = (int*)alloc((size_t)B_*S1_);
  int* idx2   = (int*)alloc((size_t)B_*S2_);
  int* knn1   = (int*)alloc((size_t)B_*S1_*KG_);
  int* knn2   = (int*)alloc((size_t)B_*S2_*KG_);
  float* gmx  = alloc((size_t)B_*S1_*128);      // 8 MB (SG2 reuses as [8192][256])
  float* gmn  = alloc((size_t)B_*S1_*128);      // 8 MB
  f16* w1p1 = (f16*)alloc(128*64/2);
  f16* w2p1 = (f16*)alloc(128*128/2);
  f16* w1p2 = (f16*)alloc(256*128/2);
  f16* w2p2 = (f16*)alloc(256*256/2);
  if (off * sizeof(float) > ws_size) return;

  float* st0 = stats + 0*512; float* st1 = stats + 1*512; float* st2 = stats + 2*512;
  float* st3 = stats + 3*512; float* st4 = stats + 4*512; float* st5 = stats + 5*512;
  float* sb0 = sb + 0*512; float* sb1 = sb + 1*512; float* sb2 = sb + 2*512;
  float* sb3 = sb + 3*512; float* sb4 = sb + 4*512; float* sb5 = sb + 5*512;

  (void)hipMemsetAsync(stats, 0, 6*512*sizeof(float), stream);

  // ---- pack weights to f16 B-fragment order ----
  pack_w_k<<<(2*8*64 +255)/256, 256, 0, stream>>>(sg1w1, w1p1, 128, 128, 0, 2*8*64);
  pack_w_k<<<(4*8*64 +255)/256, 256, 0, stream>>>(sg1w2, w2p1, 128, 128, 0, 4*8*64);
  pack_w_k<<<(4*16*64+255)/256, 256, 0, stream>>>(sg2w1, w1p2, 256, 256, 0, 4*16*64);
  pack_w_k<<<(8*16*64+255)/256, 256, 0, stream>>>(sg2w2, w2p2, 256, 256, 0, 8*16*64);

  // ---- K1 = fps1 | transpose | stem1 ----
  k1_k<<<B_ + 768 + 1024, 256, 0, stream>>>(x, idx1, nx1, xyzb, w1, st0, st0+256);
  finalize_bn_k<<<1, 256, 0, stream>>>(st0, st0+256, g1, b1, sb0, sb0+256, 64, 65536.f);

  // ---- K2 = fps2 | knn1 | stem2 ----
  k2_k<<<B_ + 4096 + 1024, 256, 0, stream>>>(x, xyzb, nx1, idx2, nx2, knn1,
      w1, sb0, sb0+256, w2, fbuf, st1, st1+256);
  finalize_bn_k<<<1, 256, 0, stream>>>(st1, st1+256, g2, b2, sb1, sb1+256, 64, 65536.f);
  bnrelu_k<<<(B_*N1_*64)/256, 256, 0, stream>>>(fbuf, sb1, sb1+256, fbuf, B_*N1_*64, 64);

  // ---- SG1 ----
  gather_rows_k<<<(B_*S1_*64)/256, 256, 0, stream>>>(fbuf, idx1, cf, B_*S1_*64, 64, S1_, N1_);
  sgm_k<64,0><<<(B_*S1_)/GPB, 256, 0, stream>>>(fbuf, cf, knn1, sg1w1, w1p1, nullptr,
      nullptr, nullptr, st2, st2+256, nullptr, nullptr, N1_, S1_);
  finalize_bn_k<<<1, 256, 0, stream>>>(st2, st2+256, sg1g1, sg1b1, sb2, sb2+256, 128, 524288.f);
  sgm_k<64,1><<<(B_*S1_)/GPB, 256, 0, stream>>>(fbuf, cf, knn1, sg1w1, w1p1, w2p1,
      sb2, sb2+256, st3, st3+256, gmx, gmn, N1_, S1_);
  finalize_bn_k<<<1, 256, 0, stream>>>(st3, st3+256, sg1g2, sg1b2, sb3, sb3+256, 128, 524288.f);
  combine_k<<<(B_*S1_*128)/256, 256, 0, stream>>>(gmx, gmn, sb3, sb3+256, f1, B_*S1_*128, 128);

  // ---- SG2 ----
  knnw_k<S1_><<<(B_*S2_)/4, 256, 0, stream>>>(nx1, nx2, S2_, knn2);
  gather_rows_k<<<(B_*S2_*128)/256, 256, 0, stream>>>(f1, idx2, cf, B_*S2_*128, 128, S2_, S1_);
  sgm_k<128,0><<<(B_*S2_)/GPB, 256, 0, stream>>>(f1, cf, knn2, sg2w1, w1p2, nullptr,
      nullptr, nullptr, st4, st4+256, nullptr, nullptr, S1_, S2_);
  finalize_bn_k<<<1, 256, 0, stream>>>(st4, st4+256, sg2g1, sg2b1, sb4, sb4+256, 256, 262144.f);
  sgm_k<128,1><<<(B_*S2_)/GPB, 256, 0, stream>>>(f1, cf, knn2, sg2w1, w1p2, w2p2,
      sb4, sb4+256, st5, st5+256, gmx, gmn, S1_, S2_);
  finalize_bn_k<<<1, 256, 0, stream>>>(st5, st5+256, sg2g2, sg2b2, sb5, sb5+256, 256, 262144.f);
  final_out_k<<<(B_*256*S2_)/256, 256, 0, stream>>>(gmx, gmn, sb5, sb5+256, (float*)d_out);
}

// Round 11
// 1429.388 us; speedup vs baseline: 1.0417x; 1.0417x over previous
//
#include <hip/hip_runtime.h>

// ---------------------------------------------------------------------------
// NeighborEmbedding — f16-MFMA grouped GEMMs + wave-per-center kNN +
// LDS-coordinate DPP-reduce FPS, multi-role fused launches:
//   K1 = fps1 | transpose | stem1   (all depend only on x)
//   K2 = fps2 | knn1 | stem2        (mutually independent)
// B=32, N=2048, SG1: s=512,K=32, 128->128, SG2: s=256,K=32, 256->256.
// ---------------------------------------------------------------------------

#define B_   32
#define N1_  2048
#define S1_  512
#define S2_  256
#define KG_  32
#define GPB  8

using f16 = _Float16;
typedef _Float16 f16x8 __attribute__((ext_vector_type(8)));
typedef _Float16 f16x4 __attribute__((ext_vector_type(4)));
typedef float    f32x4 __attribute__((ext_vector_type(4)));

// distance with FMA contraction OFF (FPS argmax / kNN selection are discrete)
__device__ __forceinline__ float dist3(float ax,float ay,float az,
                                       float bx,float by,float bz){
#pragma clang fp contract(off)
  float dx = ax - bx, dy = ay - by, dz = az - bz;
  return (dx*dx + dy*dy) + dz*dz;
}

// 64-lane max-reduce of a u64 key via DPP; lane 63 holds the max; readlane bcast.
__device__ __forceinline__ unsigned long long dpp_max_key(unsigned long long k){
  unsigned hi = (unsigned)(k >> 32), lo = (unsigned)k;
#define DPP_STEP(CTRL) { \
    unsigned h2 = (unsigned)__builtin_amdgcn_update_dpp((int)hi, (int)hi, CTRL, 0xf, 0xf, false); \
    unsigned l2 = (unsigned)__builtin_amdgcn_update_dpp((int)lo, (int)lo, CTRL, 0xf, 0xf, false); \
    if (h2 > hi || (h2 == hi && l2 > lo)){ hi = h2; lo = l2; } }
  DPP_STEP(0x111);  // row_shr:1
  DPP_STEP(0x112);  // row_shr:2
  DPP_STEP(0x114);  // row_shr:4
  DPP_STEP(0x118);  // row_shr:8
  DPP_STEP(0x142);  // row_bcast15
  DPP_STEP(0x143);  // row_bcast31
#undef DPP_STEP
  unsigned fh = (unsigned)__builtin_amdgcn_readlane((int)hi, 63);
  unsigned fl = (unsigned)__builtin_amdgcn_readlane((int)lo, 63);
  return ((unsigned long long)fh << 32) | fl;
}

// FPS LDS state: coords live in LDS (rounds 5-10 showed the allocator will
// NEVER keep them in VGPRs in this kernel shape — VGPR_Count=32 at round 10
// meant the 32-float arrays sat in scratch, ~2200 cyc/step). Stride-1 lane
// access -> 2 lanes/bank = conflict-free. Only d[PL] stays in registers.
template<int NPTS>
struct FpsSmemT {
  float xS[NPTS], yS[NPTS], zS[NPTS];
  unsigned long long keyS[2][4];
};

// ---------------------------------------------------------------------------
// FPS device body: one 4-wave block per batch. No global stores in the loop
// (round-9); coords in LDS, d in regs; key-only DPP + LDS fold; winner
// coords fetched as LDS broadcast reads xS[far] (xS read-only after init,
// so the single fold barrier covers visibility).
// PACKED: pts[(b*NPTS+i)*3+d]. !PACKED: x[(b*3+d)*NPTS+i] (same values).
template<int NPTS, int SS, bool PACKED>
__device__ __forceinline__ void dev_fps(const float* __restrict__ pts,
                                        int* __restrict__ idx_out,
                                        float* __restrict__ newxyz,
                                        int b, FpsSmemT<NPTS>& sm, int tid){
  constexpr int PL = NPTS/256;
  constexpr int ST = SS/256;
  const int lane = tid & 63, wid = tid >> 6;
  float d[PL];
  float cx, cy, cz;
  if (PACKED){
    const float* P = pts + (size_t)b*NPTS*3;
    #pragma unroll
    for (int t = 0; t < PL; ++t){
      int i = tid + 256*t;
      sm.xS[i] = P[i*3+0]; sm.yS[i] = P[i*3+1]; sm.zS[i] = P[i*3+2];
      d[t] = 1e10f;
    }
    cx = P[0]; cy = P[1]; cz = P[2];
  } else {
    const float* X0 = pts + (size_t)(b*3+0)*NPTS;
    const float* X1 = pts + (size_t)(b*3+1)*NPTS;
    const float* X2 = pts + (size_t)(b*3+2)*NPTS;
    #pragma unroll
    for (int t = 0; t < PL; ++t){
      int i = tid + 256*t;
      sm.xS[i] = X0[i]; sm.yS[i] = X1[i]; sm.zS[i] = X2[i];
      d[t] = 1e10f;
    }
    cx = X0[0]; cy = X1[0]; cz = X2[0];
  }
  int far = 0;
  int   far_st[ST];
  float cx_st[ST], cy_st[ST], cz_st[ST];
  for (int s = 0; s < SS; ++s){
    if ((s & 255) == tid){
      int u = s >> 8;
      far_st[u] = far; cx_st[u] = cx; cy_st[u] = cy; cz_st[u] = cz;
    }
    unsigned long long lkey;
    {
      float nd = fminf(d[0], dist3(sm.xS[tid], sm.yS[tid], sm.zS[tid], cx, cy, cz));
      d[0] = nd;
      lkey = ((unsigned long long)__float_as_uint(nd) << 32) | (~(unsigned)tid);
    }
    #pragma unroll
    for (int t = 1; t < PL; ++t){
      int i = tid + 256*t;
      float nd = fminf(d[t], dist3(sm.xS[i], sm.yS[i], sm.zS[i], cx, cy, cz));
      d[t] = nd;
      unsigned long long k = ((unsigned long long)__float_as_uint(nd) << 32)
                           | (~(unsigned)i);
      if (k > lkey) lkey = k;
    }
    unsigned long long wkey = dpp_max_key(lkey);
    const int buf = s & 1;
    if (lane == 0) sm.keyS[buf][wid] = wkey;
    __syncthreads();
    unsigned long long gk = sm.keyS[buf][0];
    #pragma unroll
    for (int w = 1; w < 4; ++w){
      unsigned long long k = sm.keyS[buf][w];
      if (k > gk) gk = k;
    }
    far = (int)(~(unsigned)gk);
    cx = sm.xS[far]; cy = sm.yS[far]; cz = sm.zS[far];
  }
  #pragma unroll
  for (int u = 0; u < ST; ++u){
    int s = u*256 + tid;
    idx_out[b*SS + s] = far_st[u];
    newxyz[(b*SS+s)*3+0] = cx_st[u];
    newxyz[(b*SS+s)*3+1] = cy_st[u];
    newxyz[(b*SS+s)*3+2] = cz_st[u];
  }
}

// ---------------------------------------------------------------------------
// kNN device body: one WAVE per center, register-resident, barrier-free.
template<int NPTS>
__device__ __forceinline__ void dev_knn(const float* __restrict__ pts,
                                        const float* __restrict__ ctr,
                                        int S, int* __restrict__ knn,
                                        int gblk, int tid){
  constexpr int PL = NPTS/64;
  const int lane = tid & 63;
  const int g = gblk*4 + (tid >> 6);
  const int b = g / S;
  const float cx = ctr[g*3+0], cy = ctr[g*3+1], cz = ctr[g*3+2];
  const float* P = pts + (size_t)b*NPTS*3;
  float d[PL];
  #pragma unroll
  for (int t = 0; t < PL; ++t){
    int i = lane + 64*t;
    d[t] = dist3(cx, cy, cz, P[i*3+0], P[i*3+1], P[i*3+2]);
  }
  for (int k = 0; k < KG_; ++k){
    float bv = d[0]; int bt = 0;
    #pragma unroll
    for (int t = 1; t < PL; ++t)
      if (d[t] < bv){ bv = d[t]; bt = t; }
    int bi = lane + 64*bt;
    #pragma unroll
    for (int off = 1; off < 64; off <<= 1){
      float ov = __shfl_xor(bv, off);
      int   oi = __shfl_xor(bi, off);
      if (ov < bv || (ov == bv && oi < bi)){ bv = ov; bi = oi; }
    }
    if (lane == k) knn[g*KG_ + k] = bi;
    if ((bi & 63) == lane){
      const int wt = bi >> 6;
      #pragma unroll
      for (int t = 0; t < PL; ++t)
        if (t == wt) d[t] = 3.0e38f;
    }
  }
}

template<int NPTS>
__global__ __launch_bounds__(256) void knnw_k(const float* __restrict__ pts,
                                              const float* __restrict__ ctr,
                                              int S, int* __restrict__ knn){
  dev_knn<NPTS>(pts, ctr, S, knn, blockIdx.x, threadIdx.x);
}

// ---------------------------------------------------------------------------
// K1 = fps1 | transpose | stem1 (all read only x). Blocks:
// [0,32): fps1, [32,800): transpose (768), [800,1824): stem1 (1024).
union K1Smem {
  FpsSmemT<N1_> fps;       // 24 KB + keys
  float red[64][5];
};
__global__ __launch_bounds__(256) void k1_k(const float* __restrict__ x,
                                            int* __restrict__ idx1,
                                            float* __restrict__ nx1,
                                            float* __restrict__ xyzb,
                                            const float* __restrict__ w1,
                                            float* __restrict__ ssum,
                                            float* __restrict__ ssq){
  __shared__ K1Smem sm;
  const int blk = blockIdx.x, tid = threadIdx.x;
  if (blk < B_){
    dev_fps<N1_, S1_, false>(x, idx1, nx1, blk, sm.fps, tid);
  } else if (blk < B_ + 768){
    int e = (blk - B_)*256 + tid;           // < B*N*3
    int d = e % 3; int n = (e/3) % N1_; int b = e / (3*N1_);
    xyzb[e] = x[(b*3 + d)*N1_ + n];
  } else {
    // stem1 stats: 64 rows/block, read x strided (same values as xyz rows)
    const int c  = tid & 63;
    const int sl = tid >> 6;
    const float wx = w1[c*3+0], wy = w1[c*3+1], wz = w1[c*3+2];
    const int base = (blk - (B_+768))*64 + sl*16;
    float ls = 0.f, lq = 0.f;
    for (int r = 0; r < 16; ++r){
      int m = base + r;
      int b = m >> 11, n = m & 2047;
      float xv = x[(b*3+0)*N1_ + n];
      float yv = x[(b*3+1)*N1_ + n];
      float zv = x[(b*3+2)*N1_ + n];
      float h = xv*wx + yv*wy + zv*wz;
      ls += h; lq += h*h;
    }
    sm.red[c][sl] = ls; __syncthreads();
    if (sl == 0) atomicAdd(&ssum[c], sm.red[c][0]+sm.red[c][1]+sm.red[c][2]+sm.red[c][3]);
    __syncthreads();
    sm.red[c][sl] = lq; __syncthreads();
    if (sl == 0) atomicAdd(&ssq[c], sm.red[c][0]+sm.red[c][1]+sm.red[c][2]+sm.red[c][3]);
  }
}

// ---------------------------------------------------------------------------
// K2 = fps2 | knn1 | stem2. Blocks:
// [0,32): fps2, [32,4128): knn1 (4096), [4128,5152): stem2 (1024).
union K2Smem {
  FpsSmemT<S1_> fps;       // 6 KB + keys
  struct { float As[32][68]; float Ws[32][68]; float red[64][17]; } s2;
};
__global__ __launch_bounds__(256) void k2_k(const float* __restrict__ x,
                                            const float* __restrict__ xyzb,
                                            const float* __restrict__ nx1,
                                            int* __restrict__ idx2,
                                            float* __restrict__ nx2,
                                            int* __restrict__ knn1,
                                            const float* __restrict__ w1,
                                            const float* __restrict__ s0,
                                            const float* __restrict__ b0,
                                            const float* __restrict__ w2,
                                            float* __restrict__ hout,
                                            float* __restrict__ ssum,
                                            float* __restrict__ ssq){
  __shared__ K2Smem sm;
  const int blk = blockIdx.x, tid = threadIdx.x;
  if (blk < B_){
    dev_fps<S1_, S2_, true>(nx1, idx2, nx2, blk, sm.fps, tid);
  } else if (blk < B_ + 4096){
    dev_knn<N1_>(xyzb, nx1, S1_, knn1, blk - B_, tid);
  } else {
    // stem2: 64x64 tile GEMM, recomputes layer1 from x on the fly
    const int m0 = (blk - (B_+4096)) * 64;
    const int lrow = tid >> 3;
    const int lk   = (tid & 7) * 4;
    const int tx = tid & 15, ty = tid >> 4;
    float acc[4][4];
    #pragma unroll
    for (int i=0;i<4;++i)
      #pragma unroll
      for (int j=0;j<4;++j) acc[i][j]=0.f;

    for (int k0 = 0; k0 < 64; k0 += 32){
      __syncthreads();
      #pragma unroll
      for (int p = 0; p < 2; ++p){
        int m = m0 + lrow + p*32;
        int b = m >> 11, n = m & 2047;
        float x0 = x[(b*3+0)*N1_ + n];
        float x1 = x[(b*3+1)*N1_ + n];
        float x2 = x[(b*3+2)*N1_ + n];
        #pragma unroll
        for (int j = 0; j < 4; ++j){
          int k = k0 + lk + j;
          float h = x0*w1[k*3+0] + x1*w1[k*3+1] + x2*w1[k*3+2];
          sm.s2.As[lk+j][lrow+p*32] = fmaxf(h*s0[k] + b0[k], 0.f);
        }
      }
      {
        const int cl = tid >> 2, kp = (tid & 3)*8;
        const float* wr = w2 + cl*64 + k0 + kp;
        #pragma unroll
        for (int q = 0; q < 2; ++q){
          float4 w = *reinterpret_cast<const float4*>(wr + q*4);
          sm.s2.Ws[kp+q*4+0][cl] = w.x; sm.s2.Ws[kp+q*4+1][cl] = w.y;
          sm.s2.Ws[kp+q*4+2][cl] = w.z; sm.s2.Ws[kp+q*4+3][cl] = w.w;
        }
      }
      __syncthreads();
      #pragma unroll
      for (int kk = 0; kk < 32; ++kk){
        float4 av = *reinterpret_cast<const float4*>(&sm.s2.As[kk][ty*4]);
        float4 wv = *reinterpret_cast<const float4*>(&sm.s2.Ws[kk][tx*4]);
        acc[0][0]+=av.x*wv.x; acc[0][1]+=av.x*wv.y; acc[0][2]+=av.x*wv.z; acc[0][3]+=av.x*wv.w;
        acc[1][0]+=av.y*wv.x; acc[1][1]+=av.y*wv.y; acc[1][2]+=av.y*wv.z; acc[1][3]+=av.y*wv.w;
        acc[2][0]+=av.z*wv.x; acc[2][1]+=av.z*wv.y; acc[2][2]+=av.z*wv.z; acc[2][3]+=av.z*wv.w;
        acc[3][0]+=av.w*wv.x; acc[3][1]+=av.w*wv.y; acc[3][2]+=av.w*wv.z; acc[3][3]+=av.w*wv.w;
      }
    }
    #pragma unroll
    for (int r = 0; r < 4; ++r){
      float4 o; o.x=acc[r][0]; o.y=acc[r][1]; o.z=acc[r][2]; o.w=acc[r][3];
      *reinterpret_cast<float4*>(hout + (size_t)(m0 + ty*4 + r)*64 + tx*4) = o;
    }
    __syncthreads();
    #pragma unroll
    for (int j = 0; j < 4; ++j)
      sm.s2.red[tx*4+j][ty] = acc[0][j]+acc[1][j]+acc[2][j]+acc[3][j];
    __syncthreads();
    if (tid < 64){
      float s = 0.f;
      #pragma unroll
      for (int t = 0; t < 16; ++t) s += sm.s2.red[tid][t];
      atomicAdd(&ssum[tid], s);
    }
    __syncthreads();
    #pragma unroll
    for (int j = 0; j < 4; ++j)
      sm.s2.red[tx*4+j][ty] = acc[0][j]*acc[0][j]+acc[1][j]*acc[1][j]
                            + acc[2][j]*acc[2][j]+acc[3][j]*acc[3][j];
    __syncthreads();
    if (tid < 64){
      float s = 0.f;
      #pragma unroll
      for (int t = 0; t < 16; ++t) s += sm.s2.red[tid][t];
      atomicAdd(&ssq[tid], s);
    }
  }
}

// ---------------------------------------------------------------------------
// pack fp32 weight rows into f16 B-fragment order
__global__ __launch_bounds__(256) void pack_w_k(const float* __restrict__ W,
                                                f16* __restrict__ out,
                                                int C, int Kfull, int koff,
                                                int total){
  int e = blockIdx.x*256 + threadIdx.x;
  if (e >= total) return;
  int lane = e & 63, tile = e >> 6;
  int ntiles = C/16;
  int nt = tile % ntiles, kt = tile / ntiles;
  int n = nt*16 + (lane & 15);
  int k0 = kt*32 + (lane >> 4)*8;
  const float* src = W + (size_t)n*Kfull + koff + k0;
  f16* dst = out + (size_t)e*8;
  #pragma unroll
  for (int j = 0; j < 8; ++j) dst[j] = (f16)src[j];
}

__global__ void finalize_bn_k(const float* __restrict__ ssum, const float* __restrict__ ssq,
                              const float* __restrict__ g,   const float* __restrict__ b,
                              float* __restrict__ scale, float* __restrict__ bias,
                              int C, float count){
  int c = threadIdx.x;
  if (c < C){
    double m = (double)ssum[c] / (double)count;
    double v = (double)ssq[c] / (double)count - m*m;
    if (v < 0.0) v = 0.0;
    float sc = g[c] * (float)(1.0 / sqrt(v + 1e-5));
    scale[c] = sc;
    bias[c]  = b[c] - (float)m * sc;
  }
}

__global__ __launch_bounds__(256) void bnrelu_k(const float* __restrict__ h,
                                                const float* __restrict__ sc,
                                                const float* __restrict__ bs,
                                                float* __restrict__ out, int total, int C){
  int e = blockIdx.x*256 + threadIdx.x;
  if (e < total){
    int c = e % C;
    out[e] = fmaxf(h[e]*sc[c] + bs[c], 0.f);
  }
}

__global__ __launch_bounds__(256) void gather_rows_k(const float* __restrict__ src,
                                                     const int* __restrict__ idx,
                                                     float* __restrict__ dst,
                                                     int total, int Dc, int Ssamp, int Npts){
  int e = blockIdx.x*256 + threadIdx.x;
  if (e < total){
    int g = e / Dc, c = e - g*Dc;
    int b = g / Ssamp;
    dst[e] = src[((size_t)(b*Npts + idx[g]))*Dc + c];
  }
}

// ---------------------------------------------------------------------------
// Fused SG-stage kernel, f16 MFMA (mfma_f32_16x16x32_f16). See round-4 notes.
template<int DIN, int PASS>
__global__ __launch_bounds__(256) void sgm_k(
    const float* __restrict__ f,   // [B*Npts, DIN]
    const float* __restrict__ cf,  // [B*S, DIN]
    const int* __restrict__ knn,
    const float* __restrict__ W1full,  // fp32 [C][2*DIN] (center half)
    const f16* __restrict__ W1p,       // packed rel half, K=DIN
    const f16* __restrict__ W2p,       // packed, K=C (PASS 1)
    const float* __restrict__ s1, const float* __restrict__ b1,
    float* __restrict__ ssum, float* __restrict__ ssq,
    float* __restrict__ gmx, float* __restrict__ gmn,
    int Npts, int S)
{
  constexpr int C   = 2*DIN;
  constexpr int NT  = C/16;     // n-tiles
  constexpr int KT1 = DIN/32;   // k-tiles layer1
  constexpr int KT2 = C/32;     // k-tiles layer2
  constexpr int NTW = NT/4;     // n-tiles per wave
  constexpr int RP  = DIN + 8;  // rel row pitch (halfs)
  constexpr int HP  = C + 8;    // hT row pitch (halfs)

  __shared__ f16 relS[32*RP];
  __shared__ float hcS[C];
  __shared__ float csS[DIN];
  __shared__ f16 hTS[PASS ? 32*HP : 8];

  const int tid = threadIdx.x;
  const int lane = tid & 63, wid = tid >> 6;
  const int col = lane & 15, quad = lane >> 4;

  float sAcc[NTW], qAcc[NTW];
  #pragma unroll
  for (int t = 0; t < NTW; ++t){ sAcc[t] = 0.f; qAcc[t] = 0.f; }

  for (int gi = 0; gi < GPB; ++gi){
    const int g = blockIdx.x*GPB + gi;
    const int b = g / S;
    __syncthreads();
    // ---- stage rel (f16) + center row ----
    {
      const int r = tid >> 3, part = tid & 7;
      const int j = knn[g*KG_ + r];
      const float* fr = f + (size_t)(b*Npts + j)*DIN + part*(DIN/8);
      const float* cr = cf + (size_t)g*DIN + part*(DIN/8);
      f16* dst = relS + r*RP + part*(DIN/8);
      #pragma unroll
      for (int q = 0; q < DIN/32; ++q){
        float4 fv = *reinterpret_cast<const float4*>(fr + q*4);
        float4 cv = *reinterpret_cast<const float4*>(cr + q*4);
        f16x4 hv;
        hv.x = (f16)(fv.x - cv.x); hv.y = (f16)(fv.y - cv.y);
        hv.z = (f16)(fv.z - cv.z); hv.w = (f16)(fv.w - cv.w);
        *reinterpret_cast<f16x4*>(dst + q*4) = hv;
      }
      if (tid < DIN) csS[tid] = cf[(size_t)g*DIN + tid];
    }
    __syncthreads();
    // ---- rank-1 center contribution (exact fp32) ----
    if (tid < C){
      const float* wr = W1full + (size_t)tid*C + DIN;
      float s = 0.f;
      for (int k = 0; k < DIN; k += 4){
        float4 w = *reinterpret_cast<const float4*>(wr + k);
        s += csS[k]*w.x + csS[k+1]*w.y + csS[k+2]*w.z + csS[k+3]*w.w;
      }
      hcS[tid] = s;
    }
    __syncthreads();

    // ---- layer1 A-frags ----
    f16x8 a1[2][KT1];
    #pragma unroll
    for (int mt = 0; mt < 2; ++mt)
      #pragma unroll
      for (int kt = 0; kt < KT1; ++kt)
        a1[mt][kt] = *reinterpret_cast<const f16x8*>(relS + (mt*16+col)*RP + kt*32 + quad*8);

    if (PASS == 0){
      #pragma unroll
      for (int t = 0; t < NTW; ++t){
        const int nt = wid*NTW + t;
        const float hc = hcS[nt*16 + col];
        f32x4 acc0 = {hc,hc,hc,hc}, acc1 = {hc,hc,hc,hc};
        #pragma unroll
        for (int kt = 0; kt < KT1; ++kt){
          f16x8 bf = *reinterpret_cast<const f16x8*>(W1p + ((size_t)(kt*NT + nt)*64 + lane)*8);
          acc0 = __builtin_amdgcn_mfma_f32_16x16x32_f16(a1[0][kt], bf, acc0, 0, 0, 0);
          acc1 = __builtin_amdgcn_mfma_f32_16x16x32_f16(a1[1][kt], bf, acc1, 0, 0, 0);
        }
        float s = acc0[0]+acc0[1]+acc0[2]+acc0[3] + acc1[0]+acc1[1]+acc1[2]+acc1[3];
        float q = acc0[0]*acc0[0]+acc0[1]*acc0[1]+acc0[2]*acc0[2]+acc0[3]*acc0[3]
                + acc1[0]*acc1[0]+acc1[1]*acc1[1]+acc1[2]*acc1[2]+acc1[3]*acc1[3];
        s += __shfl_xor(s, 16); s += __shfl_xor(s, 32);
        q += __shfl_xor(q, 16); q += __shfl_xor(q, 32);
        sAcc[t] += s; qAcc[t] += q;
      }
    } else {
      #pragma unroll
      for (int t = 0; t < NTW; ++t){
        const int nt = wid*NTW + t;
        const float hc = hcS[nt*16 + col];
        f32x4 acc0 = {hc,hc,hc,hc}, acc1 = {hc,hc,hc,hc};
        #pragma unroll
        for (int kt = 0; kt < KT1; ++kt){
          f16x8 bf = *reinterpret_cast<const f16x8*>(W1p + ((size_t)(kt*NT + nt)*64 + lane)*8);
          acc0 = __builtin_amdgcn_mfma_f32_16x16x32_f16(a1[0][kt], bf, acc0, 0, 0, 0);
          acc1 = __builtin_amdgcn_mfma_f32_16x16x32_f16(a1[1][kt], bf, acc1, 0, 0, 0);
        }
        const float sc = s1[nt*16+col], bs = b1[nt*16+col];
        #pragma unroll
        for (int r = 0; r < 4; ++r){
          hTS[(quad*4+r)*HP + nt*16+col]    = (f16)fmaxf(acc0[r]*sc + bs, 0.f);
          hTS[(16+quad*4+r)*HP + nt*16+col] = (f16)fmaxf(acc1[r]*sc + bs, 0.f);
        }
      }
      __syncthreads();   // hT complete (all waves)
      f16x8 a2[2][KT2];
      #pragma unroll
      for (int mt = 0; mt < 2; ++mt)
        #pragma unroll
        for (int kt = 0; kt < KT2; ++kt)
          a2[mt][kt] = *reinterpret_cast<const f16x8*>(hTS + (mt*16+col)*HP + kt*32 + quad*8);
      #pragma unroll
      for (int t = 0; t < NTW; ++t){
        const int nt = wid*NTW + t;
        f32x4 acc0 = {0.f,0.f,0.f,0.f}, acc1 = {0.f,0.f,0.f,0.f};
        #pragma unroll
        for (int kt = 0; kt < KT2; ++kt){
          f16x8 bf = *reinterpret_cast<const f16x8*>(W2p + ((size_t)(kt*NT + nt)*64 + lane)*8);
          acc0 = __builtin_amdgcn_mfma_f32_16x16x32_f16(a2[0][kt], bf, acc0, 0, 0, 0);
          acc1 = __builtin_amdgcn_mfma_f32_16x16x32_f16(a2[1][kt], bf, acc1, 0, 0, 0);
        }
        float s = acc0[0]+acc0[1]+acc0[2]+acc0[3] + acc1[0]+acc1[1]+acc1[2]+acc1[3];
        float q = acc0[0]*acc0[0]+acc0[1]*acc0[1]+acc0[2]*acc0[2]+acc0[3]*acc0[3]
                + acc1[0]*acc1[0]+acc1[1]*acc1[1]+acc1[2]*acc1[2]+acc1[3]*acc1[3];
        float mx = fmaxf(fmaxf(fmaxf(acc0[0],acc0[1]), fmaxf(acc0[2],acc0[3])),
                         fmaxf(fmaxf(acc1[0],acc1[1]), fmaxf(acc1[2],acc1[3])));
        float mn = fminf(fminf(fminf(acc0[0],acc0[1]), fminf(acc0[2],acc0[3])),
                         fminf(fminf(acc1[0],acc1[1]), fminf(acc1[2],acc1[3])));
        s += __shfl_xor(s, 16); s += __shfl_xor(s, 32);
        q += __shfl_xor(q, 16); q += __shfl_xor(q, 32);
        mx = fmaxf(mx, __shfl_xor(mx, 16)); mx = fmaxf(mx, __shfl_xor(mx, 32));
        mn = fminf(mn, __shfl_xor(mn, 16)); mn = fminf(mn, __shfl_xor(mn, 32));
        sAcc[t] += s; qAcc[t] += q;
        if (quad == 0){
          gmx[(size_t)g*C + nt*16 + col] = mx;
          gmn[(size_t)g*C + nt*16 + col] = mn;
        }
      }
    }
  } // group loop

  #pragma unroll
  for (int t = 0; t < NTW; ++t){
    const int nt = wid*NTW + t;
    if (quad == 0){
      atomicAdd(&ssum[nt*16 + col], sAcc[t]);
      atomicAdd(&ssq [nt*16 + col], qAcc[t]);
    }
  }
}

// combine: out[g][c] = relu(scale * (scale>=0 ? max : min) + bias)
__global__ __launch_bounds__(256) void combine_k(const float* __restrict__ mx,
                                                 const float* __restrict__ mn,
                                                 const float* __restrict__ sc,
                                                 const float* __restrict__ bs,
                                                 float* __restrict__ out, int total, int C){
  int e = blockIdx.x*256 + threadIdx.x;
  if (e < total){
    int c = e % C;
    float s = sc[c];
    float v = (s >= 0.f) ? mx[e] : mn[e];
    out[e] = fmaxf(s*v + bs[c], 0.f);
  }
}

// final: out[b][c][s] from group-major [b*S2+s][c]
__global__ __launch_bounds__(256) void final_out_k(const float* __restrict__ mx,
                                                   const float* __restrict__ mn,
                                                   const float* __restrict__ sc,
                                                   const float* __restrict__ bs,
                                                   float* __restrict__ out){
  int e = blockIdx.x*256 + threadIdx.x;     // < 32*256*256
  int s = e & 255;
  int c = (e >> 8) & 255;
  int b = e >> 16;
  int idx = ((b << 8) + s)*256 + c;
  float scv = sc[c];
  float v = (scv >= 0.f) ? mx[idx] : mn[idx];
  out[e] = fmaxf(scv*v + bs[c], 0.f);
}

// ---------------------------------------------------------------------------
extern "C" void kernel_launch(void* const* d_in, const int* in_sizes, int n_in,
                              void* d_out, int out_size, void* d_ws, size_t ws_size,
                              hipStream_t stream)
{
  const float* x      = (const float*)d_in[0];
  const float* w1     = (const float*)d_in[1];
  const float* g1     = (const float*)d_in[2];
  const float* b1     = (const float*)d_in[3];
  const float* w2     = (const float*)d_in[4];
  const float* g2     = (const float*)d_in[5];
  const float* b2     = (const float*)d_in[6];
  const float* sg1w1  = (const float*)d_in[7];
  const float* sg1g1  = (const float*)d_in[8];
  const float* sg1b1  = (const float*)d_in[9];
  const float* sg1w2  = (const float*)d_in[10];
  const float* sg1g2  = (const float*)d_in[11];
  const float* sg1b2  = (const float*)d_in[12];
  const float* sg2w1  = (const float*)d_in[13];
  const float* sg2g1  = (const float*)d_in[14];
  const float* sg2b1  = (const float*)d_in[15];
  const float* sg2w2  = (const float*)d_in[16];
  const float* sg2g2  = (const float*)d_in[17];
  const float* sg2b2  = (const float*)d_in[18];

  float* ws = (float*)d_ws;
  size_t off = 0;
  auto alloc = [&](size_t n){ float* p = ws + off; off += (n + 63) & ~(size_t)63; return p; };

  float* xyzb = alloc((size_t)B_*N1_*3);
  float* fbuf = alloc((size_t)B_*N1_*64);       // 16 MB
  float* f1   = alloc((size_t)B_*S1_*128);      // 8 MB
  float* cf   = alloc((size_t)B_*S1_*64);       // 4 MB (cf1; reused as cf2)
  float* nx1  = alloc((size_t)B_*S1_*3);
  float* nx2  = alloc((size_t)B_*S2_*3);
  float* stats= alloc(6*512);
  float* sb   = alloc(6*512);
  int* idx1   = (int*)alloc((size_t)B_*S1_);
  int* idx2   = (int*)alloc((size_t)B_*S2_);
  int* knn1   = (int*)alloc((size_t)B_*S1_*KG_);
  int* knn2   = (int*)alloc((size_t)B_*S2_*KG_);
  float* gmx  = alloc((size_t)B_*S1_*128);      // 8 MB (SG2 reuses as [8192][256])
  float* gmn  = alloc((size_t)B_*S1_*128);      // 8 MB
  f16* w1p1 = (f16*)alloc(128*64/2);
  f16* w2p1 = (f16*)alloc(128*128/2);
  f16* w1p2 = (f16*)alloc(256*128/2);
  f16* w2p2 = (f16*)alloc(256*256/2);
  if (off * sizeof(float) > ws_size) return;

  float* st0 = stats + 0*512; float* st1 = stats + 1*512; float* st2 = stats + 2*512;
  float* st3 = stats + 3*512; float* st4 = stats + 4*512; float* st5 = stats + 5*512;
  float* sb0 = sb + 0*512; float* sb1 = sb + 1*512; float* sb2 = sb + 2*512;
  float* sb3 = sb + 3*512; float* sb4 = sb + 4*512; float* sb5 = sb + 5*512;

  (void)hipMemsetAsync(stats, 0, 6*512*sizeof(float), stream);

  // ---- pack weights to f16 B-fragment order ----
  pack_w_k<<<(2*8*64 +255)/256, 256, 0, stream>>>(sg1w1, w1p1, 128, 128, 0, 2*8*64);
  pack_w_k<<<(4*8*64 +255)/256, 256, 0, stream>>>(sg1w2, w2p1, 128, 128, 0, 4*8*64);
  pack_w_k<<<(4*16*64+255)/256, 256, 0, stream>>>(sg2w1, w1p2, 256, 256, 0, 4*16*64);
  pack_w_k<<<(8*16*64+255)/256, 256, 0, stream>>>(sg2w2, w2p2, 256, 256, 0, 8*16*64);

  // ---- K1 = fps1 | transpose | stem1 ----
  k1_k<<<B_ + 768 + 1024, 256, 0, stream>>>(x, idx1, nx1, xyzb, w1, st0, st0+256);
  finalize_bn_k<<<1, 256, 0, stream>>>(st0, st0+256, g1, b1, sb0, sb0+256, 64, 65536.f);

  // ---- K2 = fps2 | knn1 | stem2 ----
  k2_k<<<B_ + 4096 + 1024, 256, 0, stream>>>(x, xyzb, nx1, idx2, nx2, knn1,
      w1, sb0, sb0+256, w2, fbuf, st1, st1+256);
  finalize_bn_k<<<1, 256, 0, stream>>>(st1, st1+256, g2, b2, sb1, sb1+256, 64, 65536.f);
  bnrelu_k<<<(B_*N1_*64)/256, 256, 0, stream>>>(fbuf, sb1, sb1+256, fbuf, B_*N1_*64, 64);

  // ---- SG1 ----
  gather_rows_k<<<(B_*S1_*64)/256, 256, 0, stream>>>(fbuf, idx1, cf, B_*S1_*64, 64, S1_, N1_);
  sgm_k<64,0><<<(B_*S1_)/GPB, 256, 0, stream>>>(fbuf, cf, knn1, sg1w1, w1p1, nullptr,
      nullptr, nullptr, st2, st2+256, nullptr, nullptr, N1_, S1_);
  finalize_bn_k<<<1, 256, 0, stream>>>(st2, st2+256, sg1g1, sg1b1, sb2, sb2+256, 128, 524288.f);
  sgm_k<64,1><<<(B_*S1_)/GPB, 256, 0, stream>>>(fbuf, cf, knn1, sg1w1, w1p1, w2p1,
      sb2, sb2+256, st3, st3+256, gmx, gmn, N1_, S1_);
  finalize_bn_k<<<1, 256, 0, stream>>>(st3, st3+256, sg1g2, sg1b2, sb3, sb3+256, 128, 524288.f);
  combine_k<<<(B_*S1_*128)/256, 256, 0, stream>>>(gmx, gmn, sb3, sb3+256, f1, B_*S1_*128, 128);

  // ---- SG2 ----
  knnw_k<S1_><<<(B_*S2_)/4, 256, 0, stream>>>(nx1, nx2, S2_, knn2);
  gather_rows_k<<<(B_*S2_*128)/256, 256, 0, stream>>>(f1, idx2, cf, B_*S2_*128, 128, S2_, S1_);
  sgm_k<128,0><<<(B_*S2_)/GPB, 256, 0, stream>>>(f1, cf, knn2, sg2w1, w1p2, nullptr,
      nullptr, nullptr, st4, st4+256, nullptr, nullptr, S1_, S2_);
  finalize_bn_k<<<1, 256, 0, stream>>>(st4, st4+256, sg2g1, sg2b1, sb4, sb4+256, 256, 262144.f);
  sgm_k<128,1><<<(B_*S2_)/GPB, 256, 0, stream>>>(f1, cf, knn2, sg2w1, w1p2, w2p2,
      sb4, sb4+256, st5, st5+256, gmx, gmn, S1_, S2_);
  finalize_bn_k<<<1, 256, 0, stream>>>(st5, st5+256, sg2g2, sg2b2, sb5, sb5+256, 256, 262144.f);
  final_out_k<<<(B_*256*S2_)/256, 256, 0, stream>>>(gmx, gmn, sb5, sb5+256, (float*)d_out);
}

// Round 12
// 1273.719 us; speedup vs baseline: 1.1691x; 1.1222x over previous
//
#include <hip/hip_runtime.h>

// ---------------------------------------------------------------------------
// NeighborEmbedding — f16-MFMA grouped GEMMs (optional h1 materialization) +
// wave-per-center kNN + LDS-stash DPP-reduce FPS, multi-role fused launches:
//   K1 = fps1 | transpose | stem1,  K2 = fps2 | knn1 | stem2
// B=32, N=2048, SG1: s=512,K=32, 128->128, SG2: s=256,K=32, 256->256.
// ---------------------------------------------------------------------------

#define B_   32
#define N1_  2048
#define S1_  512
#define S2_  256
#define KG_  32
#define GPB  8

using f16 = _Float16;
typedef _Float16 f16x8 __attribute__((ext_vector_type(8)));
typedef _Float16 f16x4 __attribute__((ext_vector_type(4)));
typedef float    f32x4 __attribute__((ext_vector_type(4)));

// distance with FMA contraction OFF (FPS argmax / kNN selection are discrete)
__device__ __forceinline__ float dist3(float ax,float ay,float az,
                                       float bx,float by,float bz){
#pragma clang fp contract(off)
  float dx = ax - bx, dy = ay - by, dz = az - bz;
  return (dx*dx + dy*dy) + dz*dz;
}

// 64-lane max-reduce of a u64 key via DPP; lane 63 holds the max; readlane bcast.
__device__ __forceinline__ unsigned long long dpp_max_key(unsigned long long k){
  unsigned hi = (unsigned)(k >> 32), lo = (unsigned)k;
#define DPP_STEP(CTRL) { \
    unsigned h2 = (unsigned)__builtin_amdgcn_update_dpp((int)hi, (int)hi, CTRL, 0xf, 0xf, false); \
    unsigned l2 = (unsigned)__builtin_amdgcn_update_dpp((int)lo, (int)lo, CTRL, 0xf, 0xf, false); \
    if (h2 > hi || (h2 == hi && l2 > lo)){ hi = h2; lo = l2; } }
  DPP_STEP(0x111);  // row_shr:1
  DPP_STEP(0x112);  // row_shr:2
  DPP_STEP(0x114);  // row_shr:4
  DPP_STEP(0x118);  // row_shr:8
  DPP_STEP(0x142);  // row_bcast15
  DPP_STEP(0x143);  // row_bcast31
#undef DPP_STEP
  unsigned fh = (unsigned)__builtin_amdgcn_readlane((int)hi, 63);
  unsigned fl = (unsigned)__builtin_amdgcn_readlane((int)lo, 63);
  return ((unsigned long long)fh << 32) | fl;
}

// FPS LDS state: coords in LDS (rounds 5-11: allocator never keeps them in
// VGPRs); step results ALSO in LDS (round 9-11 bug: per-thread stash arrays
// with dynamic index went to scratch -> buffer store drained by every
// step barrier). Everything the loop touches is LDS/registers only.
template<int NPTS, int SS>
struct FpsSmemT {
  float xS[NPTS], yS[NPTS], zS[NPTS];
  unsigned long long keyS[2][4];
  int   idxR[SS];
  float cxR[SS], cyR[SS], czR[SS];
};

// ---------------------------------------------------------------------------
// FPS device body: one 4-wave block per batch, zero global/scratch traffic
// inside the step loop.
// PACKED: pts[(b*NPTS+i)*3+d]. !PACKED: x[(b*3+d)*NPTS+i] (same values).
template<int NPTS, int SS, bool PACKED>
__device__ __forceinline__ void dev_fps(const float* __restrict__ pts,
                                        int* __restrict__ idx_out,
                                        float* __restrict__ newxyz,
                                        int b, FpsSmemT<NPTS,SS>& sm, int tid){
  constexpr int PL = NPTS/256;
  constexpr int ST = SS/256;
  const int lane = tid & 63, wid = tid >> 6;
  float d[PL];
  float cx, cy, cz;
  if (PACKED){
    const float* P = pts + (size_t)b*NPTS*3;
    #pragma unroll
    for (int t = 0; t < PL; ++t){
      int i = tid + 256*t;
      sm.xS[i] = P[i*3+0]; sm.yS[i] = P[i*3+1]; sm.zS[i] = P[i*3+2];
      d[t] = 1e10f;
    }
    cx = P[0]; cy = P[1]; cz = P[2];
  } else {
    const float* X0 = pts + (size_t)(b*3+0)*NPTS;
    const float* X1 = pts + (size_t)(b*3+1)*NPTS;
    const float* X2 = pts + (size_t)(b*3+2)*NPTS;
    #pragma unroll
    for (int t = 0; t < PL; ++t){
      int i = tid + 256*t;
      sm.xS[i] = X0[i]; sm.yS[i] = X1[i]; sm.zS[i] = X2[i];
      d[t] = 1e10f;
    }
    cx = X0[0]; cy = X1[0]; cz = X2[0];
  }
  int far = 0;
  for (int s = 0; s < SS; ++s){
    if (tid == 0){
      sm.idxR[s] = far; sm.cxR[s] = cx; sm.cyR[s] = cy; sm.czR[s] = cz;
    }
    unsigned long long lkey;
    {
      float nd = fminf(d[0], dist3(sm.xS[tid], sm.yS[tid], sm.zS[tid], cx, cy, cz));
      d[0] = nd;
      lkey = ((unsigned long long)__float_as_uint(nd) << 32) | (~(unsigned)tid);
    }
    #pragma unroll
    for (int t = 1; t < PL; ++t){
      int i = tid + 256*t;
      float nd = fminf(d[t], dist3(sm.xS[i], sm.yS[i], sm.zS[i], cx, cy, cz));
      d[t] = nd;
      unsigned long long k = ((unsigned long long)__float_as_uint(nd) << 32)
                           | (~(unsigned)i);
      if (k > lkey) lkey = k;
    }
    unsigned long long wkey = dpp_max_key(lkey);
    const int buf = s & 1;
    if (lane == 0) sm.keyS[buf][wid] = wkey;
    __syncthreads();
    unsigned long long gk = sm.keyS[buf][0];
    #pragma unroll
    for (int w = 1; w < 4; ++w){
      unsigned long long k = sm.keyS[buf][w];
      if (k > gk) gk = k;
    }
    far = (int)(~(unsigned)gk);
    cx = sm.xS[far]; cy = sm.yS[far]; cz = sm.zS[far];
  }
  __syncthreads();
  #pragma unroll
  for (int u = 0; u < ST; ++u){
    int s = u*256 + tid;
    idx_out[b*SS + s] = sm.idxR[s];
    newxyz[(b*SS+s)*3+0] = sm.cxR[s];
    newxyz[(b*SS+s)*3+1] = sm.cyR[s];
    newxyz[(b*SS+s)*3+2] = sm.czR[s];
  }
}

// ---------------------------------------------------------------------------
// kNN device body: one WAVE per center, register-resident, barrier-free.
template<int NPTS>
__device__ __forceinline__ void dev_knn(const float* __restrict__ pts,
                                        const float* __restrict__ ctr,
                                        int S, int* __restrict__ knn,
                                        int gblk, int tid){
  constexpr int PL = NPTS/64;
  const int lane = tid & 63;
  const int g = gblk*4 + (tid >> 6);
  const int b = g / S;
  const float cx = ctr[g*3+0], cy = ctr[g*3+1], cz = ctr[g*3+2];
  const float* P = pts + (size_t)b*NPTS*3;
  float d[PL];
  #pragma unroll
  for (int t = 0; t < PL; ++t){
    int i = lane + 64*t;
    d[t] = dist3(cx, cy, cz, P[i*3+0], P[i*3+1], P[i*3+2]);
  }
  for (int k = 0; k < KG_; ++k){
    float bv = d[0]; int bt = 0;
    #pragma unroll
    for (int t = 1; t < PL; ++t)
      if (d[t] < bv){ bv = d[t]; bt = t; }
    int bi = lane + 64*bt;
    #pragma unroll
    for (int off = 1; off < 64; off <<= 1){
      float ov = __shfl_xor(bv, off);
      int   oi = __shfl_xor(bi, off);
      if (ov < bv || (ov == bv && oi < bi)){ bv = ov; bi = oi; }
    }
    if (lane == k) knn[g*KG_ + k] = bi;
    if ((bi & 63) == lane){
      const int wt = bi >> 6;
      #pragma unroll
      for (int t = 0; t < PL; ++t)
        if (t == wt) d[t] = 3.0e38f;
    }
  }
}

template<int NPTS>
__global__ __launch_bounds__(256) void knnw_k(const float* __restrict__ pts,
                                              const float* __restrict__ ctr,
                                              int S, int* __restrict__ knn){
  dev_knn<NPTS>(pts, ctr, S, knn, blockIdx.x, threadIdx.x);
}

// ---------------------------------------------------------------------------
// K1 = fps1 | transpose | stem1. Blocks: [0,32) fps1, [32,800) transpose,
// [800,1824) stem1.
union K1Smem {
  FpsSmemT<N1_, S1_> fps;
  float red[64][5];
};
__global__ __launch_bounds__(256) void k1_k(const float* __restrict__ x,
                                            int* __restrict__ idx1,
                                            float* __restrict__ nx1,
                                            float* __restrict__ xyzb,
                                            const float* __restrict__ w1,
                                            float* __restrict__ ssum,
                                            float* __restrict__ ssq){
  __shared__ K1Smem sm;
  const int blk = blockIdx.x, tid = threadIdx.x;
  if (blk < B_){
    dev_fps<N1_, S1_, false>(x, idx1, nx1, blk, sm.fps, tid);
  } else if (blk < B_ + 768){
    int e = (blk - B_)*256 + tid;           // < B*N*3
    int d = e % 3; int n = (e/3) % N1_; int b = e / (3*N1_);
    xyzb[e] = x[(b*3 + d)*N1_ + n];
  } else {
    const int c  = tid & 63;
    const int sl = tid >> 6;
    const float wx = w1[c*3+0], wy = w1[c*3+1], wz = w1[c*3+2];
    const int base = (blk - (B_+768))*64 + sl*16;
    float ls = 0.f, lq = 0.f;
    for (int r = 0; r < 16; ++r){
      int m = base + r;
      int b = m >> 11, n = m & 2047;
      float xv = x[(b*3+0)*N1_ + n];
      float yv = x[(b*3+1)*N1_ + n];
      float zv = x[(b*3+2)*N1_ + n];
      float h = xv*wx + yv*wy + zv*wz;
      ls += h; lq += h*h;
    }
    sm.red[c][sl] = ls; __syncthreads();
    if (sl == 0) atomicAdd(&ssum[c], sm.red[c][0]+sm.red[c][1]+sm.red[c][2]+sm.red[c][3]);
    __syncthreads();
    sm.red[c][sl] = lq; __syncthreads();
    if (sl == 0) atomicAdd(&ssq[c], sm.red[c][0]+sm.red[c][1]+sm.red[c][2]+sm.red[c][3]);
  }
}

// ---------------------------------------------------------------------------
// K2 = fps2 | knn1 | stem2. Blocks: [0,32) fps2, [32,4128) knn1, [4128,5152) stem2.
union K2Smem {
  FpsSmemT<S1_, S2_> fps;
  struct { float As[32][68]; float Ws[32][68]; float red[64][17]; } s2;
};
__global__ __launch_bounds__(256) void k2_k(const float* __restrict__ x,
                                            const float* __restrict__ xyzb,
                                            const float* __restrict__ nx1,
                                            int* __restrict__ idx2,
                                            float* __restrict__ nx2,
                                            int* __restrict__ knn1,
                                            const float* __restrict__ w1,
                                            const float* __restrict__ s0,
                                            const float* __restrict__ b0,
                                            const float* __restrict__ w2,
                                            float* __restrict__ hout,
                                            float* __restrict__ ssum,
                                            float* __restrict__ ssq){
  __shared__ K2Smem sm;
  const int blk = blockIdx.x, tid = threadIdx.x;
  if (blk < B_){
    dev_fps<S1_, S2_, true>(nx1, idx2, nx2, blk, sm.fps, tid);
  } else if (blk < B_ + 4096){
    dev_knn<N1_>(xyzb, nx1, S1_, knn1, blk - B_, tid);
  } else {
    const int m0 = (blk - (B_+4096)) * 64;
    const int lrow = tid >> 3;
    const int lk   = (tid & 7) * 4;
    const int tx = tid & 15, ty = tid >> 4;
    float acc[4][4];
    #pragma unroll
    for (int i=0;i<4;++i)
      #pragma unroll
      for (int j=0;j<4;++j) acc[i][j]=0.f;

    for (int k0 = 0; k0 < 64; k0 += 32){
      __syncthreads();
      #pragma unroll
      for (int p = 0; p < 2; ++p){
        int m = m0 + lrow + p*32;
        int b = m >> 11, n = m & 2047;
        float x0 = x[(b*3+0)*N1_ + n];
        float x1 = x[(b*3+1)*N1_ + n];
        float x2 = x[(b*3+2)*N1_ + n];
        #pragma unroll
        for (int j = 0; j < 4; ++j){
          int k = k0 + lk + j;
          float h = x0*w1[k*3+0] + x1*w1[k*3+1] + x2*w1[k*3+2];
          sm.s2.As[lk+j][lrow+p*32] = fmaxf(h*s0[k] + b0[k], 0.f);
        }
      }
      {
        const int cl = tid >> 2, kp = (tid & 3)*8;
        const float* wr = w2 + cl*64 + k0 + kp;
        #pragma unroll
        for (int q = 0; q < 2; ++q){
          float4 w = *reinterpret_cast<const float4*>(wr + q*4);
          sm.s2.Ws[kp+q*4+0][cl] = w.x; sm.s2.Ws[kp+q*4+1][cl] = w.y;
          sm.s2.Ws[kp+q*4+2][cl] = w.z; sm.s2.Ws[kp+q*4+3][cl] = w.w;
        }
      }
      __syncthreads();
      #pragma unroll
      for (int kk = 0; kk < 32; ++kk){
        float4 av = *reinterpret_cast<const float4*>(&sm.s2.As[kk][ty*4]);
        float4 wv = *reinterpret_cast<const float4*>(&sm.s2.Ws[kk][tx*4]);
        acc[0][0]+=av.x*wv.x; acc[0][1]+=av.x*wv.y; acc[0][2]+=av.x*wv.z; acc[0][3]+=av.x*wv.w;
        acc[1][0]+=av.y*wv.x; acc[1][1]+=av.y*wv.y; acc[1][2]+=av.y*wv.z; acc[1][3]+=av.y*wv.w;
        acc[2][0]+=av.z*wv.x; acc[2][1]+=av.z*wv.y; acc[2][2]+=av.z*wv.z; acc[2][3]+=av.z*wv.w;
        acc[3][0]+=av.w*wv.x; acc[3][1]+=av.w*wv.y; acc[3][2]+=av.w*wv.z; acc[3][3]+=av.w*wv.w;
      }
    }
    #pragma unroll
    for (int r = 0; r < 4; ++r){
      float4 o; o.x=acc[r][0]; o.y=acc[r][1]; o.z=acc[r][2]; o.w=acc[r][3];
      *reinterpret_cast<float4*>(hout + (size_t)(m0 + ty*4 + r)*64 + tx*4) = o;
    }
    __syncthreads();
    #pragma unroll
    for (int j = 0; j < 4; ++j)
      sm.s2.red[tx*4+j][ty] = acc[0][j]+acc[1][j]+acc[2][j]+acc[3][j];
    __syncthreads();
    if (tid < 64){
      float s = 0.f;
      #pragma unroll
      for (int t = 0; t < 16; ++t) s += sm.s2.red[tid][t];
      atomicAdd(&ssum[tid], s);
    }
    __syncthreads();
    #pragma unroll
    for (int j = 0; j < 4; ++j)
      sm.s2.red[tx*4+j][ty] = acc[0][j]*acc[0][j]+acc[1][j]*acc[1][j]
                            + acc[2][j]*acc[2][j]+acc[3][j]*acc[3][j];
    __syncthreads();
    if (tid < 64){
      float s = 0.f;
      #pragma unroll
      for (int t = 0; t < 16; ++t) s += sm.s2.red[tid][t];
      atomicAdd(&ssq[tid], s);
    }
  }
}

// ---------------------------------------------------------------------------
// pack fp32 weight rows into f16 B-fragment order
__global__ __launch_bounds__(256) void pack_w_k(const float* __restrict__ W,
                                                f16* __restrict__ out,
                                                int C, int Kfull, int koff,
                                                int total){
  int e = blockIdx.x*256 + threadIdx.x;
  if (e >= total) return;
  int lane = e & 63, tile = e >> 6;
  int ntiles = C/16;
  int nt = tile % ntiles, kt = tile / ntiles;
  int n = nt*16 + (lane & 15);
  int k0 = kt*32 + (lane >> 4)*8;
  const float* src = W + (size_t)n*Kfull + koff + k0;
  f16* dst = out + (size_t)e*8;
  #pragma unroll
  for (int j = 0; j < 8; ++j) dst[j] = (f16)src[j];
}

__global__ void finalize_bn_k(const float* __restrict__ ssum, const float* __restrict__ ssq,
                              const float* __restrict__ g,   const float* __restrict__ b,
                              float* __restrict__ scale, float* __restrict__ bias,
                              int C, float count){
  int c = threadIdx.x;
  if (c < C){
    double m = (double)ssum[c] / (double)count;
    double v = (double)ssq[c] / (double)count - m*m;
    if (v < 0.0) v = 0.0;
    float sc = g[c] * (float)(1.0 / sqrt(v + 1e-5));
    scale[c] = sc;
    bias[c]  = b[c] - (float)m * sc;
  }
}

__global__ __launch_bounds__(256) void bnrelu_k(const float* __restrict__ h,
                                                const float* __restrict__ sc,
                                                const float* __restrict__ bs,
                                                float* __restrict__ out, int total, int C){
  int e = blockIdx.x*256 + threadIdx.x;
  if (e < total){
    int c = e % C;
    out[e] = fmaxf(h[e]*sc[c] + bs[c], 0.f);
  }
}

__global__ __launch_bounds__(256) void gather_rows_k(const float* __restrict__ src,
                                                     const int* __restrict__ idx,
                                                     float* __restrict__ dst,
                                                     int total, int Dc, int Ssamp, int Npts){
  int e = blockIdx.x*256 + threadIdx.x;
  if (e < total){
    int g = e / Dc, c = e - g*Dc;
    int b = g / Ssamp;
    dst[e] = src[((size_t)(b*Npts + idx[g]))*Dc + c];
  }
}

// ---------------------------------------------------------------------------
// Fused SG-stage kernel, f16 MFMA. MAT=1: PASS0 stores raw h1 (f16) to h1g;
// PASS1 skips gather/staging/layer1 and loads h1 from h1g instead.
template<int DIN, int PASS, int MAT>
__global__ __launch_bounds__(256) void sgm_k(
    const float* __restrict__ f,   // [B*Npts, DIN]
    const float* __restrict__ cf,  // [B*S, DIN]
    const int* __restrict__ knn,
    const float* __restrict__ W1full,  // fp32 [C][2*DIN] (center half)
    const f16* __restrict__ W1p,       // packed rel half, K=DIN
    const f16* __restrict__ W2p,       // packed, K=C (PASS 1)
    const float* __restrict__ s1, const float* __restrict__ b1,
    float* __restrict__ ssum, float* __restrict__ ssq,
    float* __restrict__ gmx, float* __restrict__ gmn,
    f16* __restrict__ h1g,
    int Npts, int S)
{
  constexpr int C   = 2*DIN;
  constexpr int NT  = C/16;     // n-tiles
  constexpr int KT1 = DIN/32;   // k-tiles layer1
  constexpr int KT2 = C/32;     // k-tiles layer2
  constexpr int NTW = NT/4;     // n-tiles per wave
  constexpr int RP  = DIN + 8;  // rel row pitch (halfs)
  constexpr int HP  = C + 8;    // hT row pitch (halfs)

  __shared__ f16 relS[(PASS==1 && MAT==1) ? 8 : 32*RP];
  __shared__ float hcS[C];
  __shared__ float csS[DIN];
  __shared__ f16 hTS[PASS ? 32*HP : 8];

  const int tid = threadIdx.x;
  const int lane = tid & 63, wid = tid >> 6;
  const int col = lane & 15, quad = lane >> 4;

  float sAcc[NTW], qAcc[NTW];
  #pragma unroll
  for (int t = 0; t < NTW; ++t){ sAcc[t] = 0.f; qAcc[t] = 0.f; }

  for (int gi = 0; gi < GPB; ++gi){
    const int g = blockIdx.x*GPB + gi;
    const int b = g / S;
    __syncthreads();

    if (!(PASS == 1 && MAT == 1)){
      // ---- stage rel (f16) + center row ----
      {
        const int r = tid >> 3, part = tid & 7;
        const int j = knn[g*KG_ + r];
        const float* fr = f + (size_t)(b*Npts + j)*DIN + part*(DIN/8);
        const float* cr = cf + (size_t)g*DIN + part*(DIN/8);
        f16* dst = relS + r*RP + part*(DIN/8);
        #pragma unroll
        for (int q = 0; q < DIN/32; ++q){
          float4 fv = *reinterpret_cast<const float4*>(fr + q*4);
          float4 cv = *reinterpret_cast<const float4*>(cr + q*4);
          f16x4 hv;
          hv.x = (f16)(fv.x - cv.x); hv.y = (f16)(fv.y - cv.y);
          hv.z = (f16)(fv.z - cv.z); hv.w = (f16)(fv.w - cv.w);
          *reinterpret_cast<f16x4*>(dst + q*4) = hv;
        }
        if (tid < DIN) csS[tid] = cf[(size_t)g*DIN + tid];
      }
      __syncthreads();
      // ---- rank-1 center contribution (exact fp32) ----
      if (tid < C){
        const float* wr = W1full + (size_t)tid*C + DIN;
        float s = 0.f;
        for (int k = 0; k < DIN; k += 4){
          float4 w = *reinterpret_cast<const float4*>(wr + k);
          s += csS[k]*w.x + csS[k+1]*w.y + csS[k+2]*w.z + csS[k+3]*w.w;
        }
        hcS[tid] = s;
      }
      __syncthreads();
    }

    if (PASS == 0){
      // ---- layer1 A-frags ----
      f16x8 a1[2][KT1];
      #pragma unroll
      for (int mt = 0; mt < 2; ++mt)
        #pragma unroll
        for (int kt = 0; kt < KT1; ++kt)
          a1[mt][kt] = *reinterpret_cast<const f16x8*>(relS + (mt*16+col)*RP + kt*32 + quad*8);
      #pragma unroll
      for (int t = 0; t < NTW; ++t){
        const int nt = wid*NTW + t;
        const float hc = hcS[nt*16 + col];
        f32x4 acc0 = {hc,hc,hc,hc}, acc1 = {hc,hc,hc,hc};
        #pragma unroll
        for (int kt = 0; kt < KT1; ++kt){
          f16x8 bf = *reinterpret_cast<const f16x8*>(W1p + ((size_t)(kt*NT + nt)*64 + lane)*8);
          acc0 = __builtin_amdgcn_mfma_f32_16x16x32_f16(a1[0][kt], bf, acc0, 0, 0, 0);
          acc1 = __builtin_amdgcn_mfma_f32_16x16x32_f16(a1[1][kt], bf, acc1, 0, 0, 0);
        }
        float s = acc0[0]+acc0[1]+acc0[2]+acc0[3] + acc1[0]+acc1[1]+acc1[2]+acc1[3];
        float q = acc0[0]*acc0[0]+acc0[1]*acc0[1]+acc0[2]*acc0[2]+acc0[3]*acc0[3]
                + acc1[0]*acc1[0]+acc1[1]*acc1[1]+acc1[2]*acc1[2]+acc1[3]*acc1[3];
        s += __shfl_xor(s, 16); s += __shfl_xor(s, 32);
        q += __shfl_xor(q, 16); q += __shfl_xor(q, 32);
        sAcc[t] += s; qAcc[t] += q;
        if (MAT == 1){
          #pragma unroll
          for (int r = 0; r < 4; ++r){
            h1g[((size_t)g*32 + quad*4+r)*C + nt*16+col]    = (f16)acc0[r];
            h1g[((size_t)g*32 + 16+quad*4+r)*C + nt*16+col] = (f16)acc1[r];
          }
        }
      }
    } else {
      if (MAT == 1){
        // ---- load h1 from global, bnrelu -> hTS ----
        const int r = tid >> 3, part = tid & 7;
        const f16* src = h1g + ((size_t)g*32 + r)*C + part*(C/8);
        f16* dst = hTS + r*HP + part*(C/8);
        #pragma unroll
        for (int q = 0; q < C/32; ++q){
          f16x4 hv = *reinterpret_cast<const f16x4*>(src + q*4);
          float4 sc4 = *reinterpret_cast<const float4*>(s1 + part*(C/8) + q*4);
          float4 bs4 = *reinterpret_cast<const float4*>(b1 + part*(C/8) + q*4);
          f16x4 o;
          o.x = (f16)fmaxf((float)hv.x*sc4.x + bs4.x, 0.f);
          o.y = (f16)fmaxf((float)hv.y*sc4.y + bs4.y, 0.f);
          o.z = (f16)fmaxf((float)hv.z*sc4.z + bs4.z, 0.f);
          o.w = (f16)fmaxf((float)hv.w*sc4.w + bs4.w, 0.f);
          *reinterpret_cast<f16x4*>(dst + q*4) = o;
        }
      } else {
        // ---- recompute layer1, bnrelu -> hTS ----
        f16x8 a1[2][KT1];
        #pragma unroll
        for (int mt = 0; mt < 2; ++mt)
          #pragma unroll
          for (int kt = 0; kt < KT1; ++kt)
            a1[mt][kt] = *reinterpret_cast<const f16x8*>(relS + (mt*16+col)*RP + kt*32 + quad*8);
        #pragma unroll
        for (int t = 0; t < NTW; ++t){
          const int nt = wid*NTW + t;
          const float hc = hcS[nt*16 + col];
          f32x4 acc0 = {hc,hc,hc,hc}, acc1 = {hc,hc,hc,hc};
          #pragma unroll
          for (int kt = 0; kt < KT1; ++kt){
            f16x8 bf = *reinterpret_cast<const f16x8*>(W1p + ((size_t)(kt*NT + nt)*64 + lane)*8);
            acc0 = __builtin_amdgcn_mfma_f32_16x16x32_f16(a1[0][kt], bf, acc0, 0, 0, 0);
            acc1 = __builtin_amdgcn_mfma_f32_16x16x32_f16(a1[1][kt], bf, acc1, 0, 0, 0);
          }
          const float sc = s1[nt*16+col], bs = b1[nt*16+col];
          #pragma unroll
          for (int r = 0; r < 4; ++r){
            hTS[(quad*4+r)*HP + nt*16+col]    = (f16)fmaxf(acc0[r]*sc + bs, 0.f);
            hTS[(16+quad*4+r)*HP + nt*16+col] = (f16)fmaxf(acc1[r]*sc + bs, 0.f);
          }
        }
      }
      __syncthreads();   // hTS complete
      f16x8 a2[2][KT2];
      #pragma unroll
      for (int mt = 0; mt < 2; ++mt)
        #pragma unroll
        for (int kt = 0; kt < KT2; ++kt)
          a2[mt][kt] = *reinterpret_cast<const f16x8*>(hTS + (mt*16+col)*HP + kt*32 + quad*8);
      #pragma unroll
      for (int t = 0; t < NTW; ++t){
        const int nt = wid*NTW + t;
        f32x4 acc0 = {0.f,0.f,0.f,0.f}, acc1 = {0.f,0.f,0.f,0.f};
        #pragma unroll
        for (int kt = 0; kt < KT2; ++kt){
          f16x8 bf = *reinterpret_cast<const f16x8*>(W2p + ((size_t)(kt*NT + nt)*64 + lane)*8);
          acc0 = __builtin_amdgcn_mfma_f32_16x16x32_f16(a2[0][kt], bf, acc0, 0, 0, 0);
          acc1 = __builtin_amdgcn_mfma_f32_16x16x32_f16(a2[1][kt], bf, acc1, 0, 0, 0);
        }
        float s = acc0[0]+acc0[1]+acc0[2]+acc0[3] + acc1[0]+acc1[1]+acc1[2]+acc1[3];
        float q = acc0[0]*acc0[0]+acc0[1]*acc0[1]+acc0[2]*acc0[2]+acc0[3]*acc0[3]
                + acc1[0]*acc1[0]+acc1[1]*acc1[1]+acc1[2]*acc1[2]+acc1[3]*acc1[3];
        float mx = fmaxf(fmaxf(fmaxf(acc0[0],acc0[1]), fmaxf(acc0[2],acc0[3])),
                         fmaxf(fmaxf(acc1[0],acc1[1]), fmaxf(acc1[2],acc1[3])));
        float mn = fminf(fminf(fminf(acc0[0],acc0[1]), fminf(acc0[2],acc0[3])),
                         fminf(fminf(acc1[0],acc1[1]), fminf(acc1[2],acc1[3])));
        s += __shfl_xor(s, 16); s += __shfl_xor(s, 32);
        q += __shfl_xor(q, 16); q += __shfl_xor(q, 32);
        mx = fmaxf(mx, __shfl_xor(mx, 16)); mx = fmaxf(mx, __shfl_xor(mx, 32));
        mn = fminf(mn, __shfl_xor(mn, 16)); mn = fminf(mn, __shfl_xor(mn, 32));
        sAcc[t] += s; qAcc[t] += q;
        if (quad == 0){
          gmx[(size_t)g*C + nt*16 + col] = mx;
          gmn[(size_t)g*C + nt*16 + col] = mn;
        }
      }
    }
  } // group loop

  #pragma unroll
  for (int t = 0; t < NTW; ++t){
    const int nt = wid*NTW + t;
    if (quad == 0){
      atomicAdd(&ssum[nt*16 + col], sAcc[t]);
      atomicAdd(&ssq [nt*16 + col], qAcc[t]);
    }
  }
}

// combine: out[g][c] = relu(scale * (scale>=0 ? max : min) + bias)
__global__ __launch_bounds__(256) void combine_k(const float* __restrict__ mx,
                                                 const float* __restrict__ mn,
                                                 const float* __restrict__ sc,
                                                 const float* __restrict__ bs,
                                                 float* __restrict__ out, int total, int C){
  int e = blockIdx.x*256 + threadIdx.x;
  if (e < total){
    int c = e % C;
    float s = sc[c];
    float v = (s >= 0.f) ? mx[e] : mn[e];
    out[e] = fmaxf(s*v + bs[c], 0.f);
  }
}

// final: out[b][c][s] from group-major [b*S2+s][c]
__global__ __launch_bounds__(256) void final_out_k(const float* __restrict__ mx,
                                                   const float* __restrict__ mn,
                                                   const float* __restrict__ sc,
                                                   const float* __restrict__ bs,
                                                   float* __restrict__ out){
  int e = blockIdx.x*256 + threadIdx.x;     // < 32*256*256
  int s = e & 255;
  int c = (e >> 8) & 255;
  int b = e >> 16;
  int idx = ((b << 8) + s)*256 + c;
  float scv = sc[c];
  float v = (scv >= 0.f) ? mx[idx] : mn[idx];
  out[e] = fmaxf(scv*v + bs[c], 0.f);
}

// ---------------------------------------------------------------------------
extern "C" void kernel_launch(void* const* d_in, const int* in_sizes, int n_in,
                              void* d_out, int out_size, void* d_ws, size_t ws_size,
                              hipStream_t stream)
{
  const float* x      = (const float*)d_in[0];
  const float* w1     = (const float*)d_in[1];
  const float* g1     = (const float*)d_in[2];
  const float* b1     = (const float*)d_in[3];
  const float* w2     = (const float*)d_in[4];
  const float* g2     = (const float*)d_in[5];
  const float* b2     = (const float*)d_in[6];
  const float* sg1w1  = (const float*)d_in[7];
  const float* sg1g1  = (const float*)d_in[8];
  const float* sg1b1  = (const float*)d_in[9];
  const float* sg1w2  = (const float*)d_in[10];
  const float* sg1g2  = (const float*)d_in[11];
  const float* sg1b2  = (const float*)d_in[12];
  const float* sg2w1  = (const float*)d_in[13];
  const float* sg2g1  = (const float*)d_in[14];
  const float* sg2b1  = (const float*)d_in[15];
  const float* sg2w2  = (const float*)d_in[16];
  const float* sg2g2  = (const float*)d_in[17];
  const float* sg2b2  = (const float*)d_in[18];

  float* ws = (float*)d_ws;
  size_t off = 0;
  auto alloc = [&](size_t n){ float* p = ws + off; off += (n + 63) & ~(size_t)63; return p; };

  float* xyzb = alloc((size_t)B_*N1_*3);
  float* fbuf = alloc((size_t)B_*N1_*64);       // 16 MB
  float* f1   = alloc((size_t)B_*S1_*128);      // 8 MB
  float* cf   = alloc((size_t)B_*S1_*64);       // 4 MB
  float* nx1  = alloc((size_t)B_*S1_*3);
  float* nx2  = alloc((size_t)B_*S2_*3);
  float* stats= alloc(6*512);
  float* sb   = alloc(6*512);
  int* idx1   = (int*)alloc((size_t)B_*S1_);
  int* idx2   = (int*)alloc((size_t)B_*S2_);
  int* knn1   = (int*)alloc((size_t)B_*S1_*KG_);
  int* knn2   = (int*)alloc((size_t)B_*S2_*KG_);
  float* gmx  = alloc((size_t)B_*S1_*128);      // 8 MB
  float* gmn  = alloc((size_t)B_*S1_*128);      // 8 MB
  f16* w1p1 = (f16*)alloc(128*64/2);
  f16* w2p1 = (f16*)alloc(128*128/2);
  f16* w1p2 = (f16*)alloc(256*128/2);
  f16* w2p2 = (f16*)alloc(256*256/2);
  if (off * sizeof(float) > ws_size) return;

  // optional h1 materialization buffer (134 MB as f16); SG2 reuses it
  const size_t h1_halfs  = (size_t)B_*S1_*KG_*128;   // == B*S2*KG*256
  const bool   mat = ((off + h1_halfs/2) * sizeof(float) <= ws_size);
  f16* hbuf = mat ? (f16*)alloc(h1_halfs/2) : nullptr;

  float* st0 = stats + 0*512; float* st1 = stats + 1*512; float* st2 = stats + 2*512;
  float* st3 = stats + 3*512; float* st4 = stats + 4*512; float* st5 = stats + 5*512;
  float* sb0 = sb + 0*512; float* sb1 = sb + 1*512; float* sb2 = sb + 2*512;
  float* sb3 = sb + 3*512; float* sb4 = sb + 4*512; float* sb5 = sb + 5*512;

  (void)hipMemsetAsync(stats, 0, 6*512*sizeof(float), stream);

  // ---- pack weights to f16 B-fragment order ----
  pack_w_k<<<(2*8*64 +255)/256, 256, 0, stream>>>(sg1w1, w1p1, 128, 128, 0, 2*8*64);
  pack_w_k<<<(4*8*64 +255)/256, 256, 0, stream>>>(sg1w2, w2p1, 128, 128, 0, 4*8*64);
  pack_w_k<<<(4*16*64+255)/256, 256, 0, stream>>>(sg2w1, w1p2, 256, 256, 0, 4*16*64);
  pack_w_k<<<(8*16*64+255)/256, 256, 0, stream>>>(sg2w2, w2p2, 256, 256, 0, 8*16*64);

  // ---- K1 = fps1 | transpose | stem1 ----
  k1_k<<<B_ + 768 + 1024, 256, 0, stream>>>(x, idx1, nx1, xyzb, w1, st0, st0+256);
  finalize_bn_k<<<1, 256, 0, stream>>>(st0, st0+256, g1, b1, sb0, sb0+256, 64, 65536.f);

  // ---- K2 = fps2 | knn1 | stem2 ----
  k2_k<<<B_ + 4096 + 1024, 256, 0, stream>>>(x, xyzb, nx1, idx2, nx2, knn1,
      w1, sb0, sb0+256, w2, fbuf, st1, st1+256);
  finalize_bn_k<<<1, 256, 0, stream>>>(st1, st1+256, g2, b2, sb1, sb1+256, 64, 65536.f);
  bnrelu_k<<<(B_*N1_*64)/256, 256, 0, stream>>>(fbuf, sb1, sb1+256, fbuf, B_*N1_*64, 64);

  // ---- SG1 ----
  gather_rows_k<<<(B_*S1_*64)/256, 256, 0, stream>>>(fbuf, idx1, cf, B_*S1_*64, 64, S1_, N1_);
  if (mat){
    sgm_k<64,0,1><<<(B_*S1_)/GPB, 256, 0, stream>>>(fbuf, cf, knn1, sg1w1, w1p1, nullptr,
        nullptr, nullptr, st2, st2+256, nullptr, nullptr, hbuf, N1_, S1_);
  } else {
    sgm_k<64,0,0><<<(B_*S1_)/GPB, 256, 0, stream>>>(fbuf, cf, knn1, sg1w1, w1p1, nullptr,
        nullptr, nullptr, st2, st2+256, nullptr, nullptr, nullptr, N1_, S1_);
  }
  finalize_bn_k<<<1, 256, 0, stream>>>(st2, st2+256, sg1g1, sg1b1, sb2, sb2+256, 128, 524288.f);
  if (mat){
    sgm_k<64,1,1><<<(B_*S1_)/GPB, 256, 0, stream>>>(fbuf, cf, knn1, sg1w1, w1p1, w2p1,
        sb2, sb2+256, st3, st3+256, gmx, gmn, hbuf, N1_, S1_);
  } else {
    sgm_k<64,1,0><<<(B_*S1_)/GPB, 256, 0, stream>>>(fbuf, cf, knn1, sg1w1, w1p1, w2p1,
        sb2, sb2+256, st3, st3+256, gmx, gmn, nullptr, N1_, S1_);
  }
  finalize_bn_k<<<1, 256, 0, stream>>>(st3, st3+256, sg1g2, sg1b2, sb3, sb3+256, 128, 524288.f);
  combine_k<<<(B_*S1_*128)/256, 256, 0, stream>>>(gmx, gmn, sb3, sb3+256, f1, B_*S1_*128, 128);

  // ---- SG2 ----
  knnw_k<S1_><<<(B_*S2_)/4, 256, 0, stream>>>(nx1, nx2, S2_, knn2);
  gather_rows_k<<<(B_*S2_*128)/256, 256, 0, stream>>>(f1, idx2, cf, B_*S2_*128, 128, S2_, S1_);
  if (mat){
    sgm_k<128,0,1><<<(B_*S2_)/GPB, 256, 0, stream>>>(f1, cf, knn2, sg2w1, w1p2, nullptr,
        nullptr, nullptr, st4, st4+256, nullptr, nullptr, hbuf, S1_, S2_);
  } else {
    sgm_k<128,0,0><<<(B_*S2_)/GPB, 256, 0, stream>>>(f1, cf, knn2, sg2w1, w1p2, nullptr,
        nullptr, nullptr, st4, st4+256, nullptr, nullptr, nullptr, S1_, S2_);
  }
  finalize_bn_k<<<1, 256, 0, stream>>>(st4, st4+256, sg2g1, sg2b1, sb4, sb4+256, 256, 262144.f);
  if (mat){
    sgm_k<128,1,1><<<(B_*S2_)/GPB, 256, 0, stream>>>(f1, cf, knn2, sg2w1, w1p2, w2p2,
        sb4, sb4+256, st5, st5+256, gmx, gmn, hbuf, S1_, S2_);
  } else {
    sgm_k<128,1,0><<<(B_*S2_)/GPB, 256, 0, stream>>>(f1, cf, knn2, sg2w1, w1p2, w2p2,
        sb4, sb4+256, st5, st5+256, gmx, gmn, nullptr, S1_, S2_);
  }
  finalize_bn_k<<<1, 256, 0, stream>>>(st5, st5+256, sg2g2, sg2b2, sb5, sb5+256, 256, 262144.f);
  final_out_k<<<(B_*256*S2_)/256, 256, 0, stream>>>(gmx, gmn, sb5, sb5+256, (float*)d_out);
}

// Round 13
// 1214.216 us; speedup vs baseline: 1.2263x; 1.0490x over previous
//
#include <hip/hip_runtime.h>

// ---------------------------------------------------------------------------
// NeighborEmbedding — f16-MFMA grouped GEMMs (h1 materialization) +
// DPP-min kNN + register-scan DPP FPS, multi-role fused launches:
//   K1 = fps1 | transpose | stem1,  K2 = fps2 | knn1 | stem2
// B=32, N=2048, SG1: s=512,K=32, 128->128, SG2: s=256,K=32, 256->256.
// ---------------------------------------------------------------------------

#define B_   32
#define N1_  2048
#define S1_  512
#define S2_  256
#define KG_  32
#define GPB  8

using f16 = _Float16;
typedef _Float16 f16x8 __attribute__((ext_vector_type(8)));
typedef _Float16 f16x4 __attribute__((ext_vector_type(4)));
typedef float    f32x4 __attribute__((ext_vector_type(4)));

// distance with FMA contraction OFF (FPS argmax / kNN selection are discrete)
__device__ __forceinline__ float dist3(float ax,float ay,float az,
                                       float bx,float by,float bz){
#pragma clang fp contract(off)
  float dx = ax - bx, dy = ay - by, dz = az - bz;
  return (dx*dx + dy*dy) + dz*dz;
}

// 64-lane max-reduce of a u64 key via DPP; lane 63 holds the max; readlane bcast.
__device__ __forceinline__ unsigned long long dpp_max_key(unsigned long long k){
  unsigned hi = (unsigned)(k >> 32), lo = (unsigned)k;
#define DPP_STEP(CTRL) { \
    unsigned h2 = (unsigned)__builtin_amdgcn_update_dpp((int)hi, (int)hi, CTRL, 0xf, 0xf, false); \
    unsigned l2 = (unsigned)__builtin_amdgcn_update_dpp((int)lo, (int)lo, CTRL, 0xf, 0xf, false); \
    if (h2 > hi || (h2 == hi && l2 > lo)){ hi = h2; lo = l2; } }
  DPP_STEP(0x111);  // row_shr:1
  DPP_STEP(0x112);  // row_shr:2
  DPP_STEP(0x114);  // row_shr:4
  DPP_STEP(0x118);  // row_shr:8
  DPP_STEP(0x142);  // row_bcast15
  DPP_STEP(0x143);  // row_bcast31
#undef DPP_STEP
  unsigned fh = (unsigned)__builtin_amdgcn_readlane((int)hi, 63);
  unsigned fl = (unsigned)__builtin_amdgcn_readlane((int)lo, 63);
  return ((unsigned long long)fh << 32) | fl;
}

// 64-lane MIN-reduce (same verified network, min combine).
__device__ __forceinline__ unsigned long long dpp_min_key(unsigned long long k){
  unsigned hi = (unsigned)(k >> 32), lo = (unsigned)k;
#define DPP_STEP(CTRL) { \
    unsigned h2 = (unsigned)__builtin_amdgcn_update_dpp((int)hi, (int)hi, CTRL, 0xf, 0xf, false); \
    unsigned l2 = (unsigned)__builtin_amdgcn_update_dpp((int)lo, (int)lo, CTRL, 0xf, 0xf, false); \
    if (h2 < hi || (h2 == hi && l2 < lo)){ hi = h2; lo = l2; } }
  DPP_STEP(0x111);
  DPP_STEP(0x112);
  DPP_STEP(0x114);
  DPP_STEP(0x118);
  DPP_STEP(0x142);
  DPP_STEP(0x143);
#undef DPP_STEP
  unsigned fh = (unsigned)__builtin_amdgcn_readlane((int)hi, 63);
  unsigned fl = (unsigned)__builtin_amdgcn_readlane((int)lo, 63);
  return ((unsigned long long)fh << 32) | fl;
}

// FPS LDS: coords kept for the xS[far] broadcast only (3 reads/step);
// the hot scan runs from asm-pinned REGISTERS (round-12 finding: the
// 96 ds_read_b32/step of an LDS/scratch scan saturate the shared LDS
// pipe -> ~1900 cyc/step; register scan removes them entirely).
template<int NPTS, int SS>
struct FpsSmemT {
  float xS[NPTS], yS[NPTS], zS[NPTS];
  unsigned long long keyS[2][4];
  int   idxR[SS];
  float cxR[SS], cyR[SS], czR[SS];
};

// ---------------------------------------------------------------------------
// FPS device body: one 4-wave block per batch; zero global/scratch traffic
// inside the step loop; scan coords pinned in VGPRs (PL=NPTS/256 <= 8 ->
// 24 coord + 8 dist floats/thread, fits default budget once pinned).
template<int NPTS, int SS, bool PACKED>
__device__ __forceinline__ void dev_fps(const float* __restrict__ pts,
                                        int* __restrict__ idx_out,
                                        float* __restrict__ newxyz,
                                        int b, FpsSmemT<NPTS,SS>& sm, int tid){
  constexpr int PL = NPTS/256;
  constexpr int ST = SS/256;
  const int lane = tid & 63, wid = tid >> 6;
  float px[PL], py[PL], pz[PL], d[PL];
  float cx, cy, cz;
  if (PACKED){
    const float* P = pts + (size_t)b*NPTS*3;
    #pragma unroll
    for (int t = 0; t < PL; ++t){
      int i = tid + 256*t;
      px[t] = P[i*3+0]; py[t] = P[i*3+1]; pz[t] = P[i*3+2];
      sm.xS[i] = px[t]; sm.yS[i] = py[t]; sm.zS[i] = pz[t];
      d[t] = 1e10f;
    }
    cx = P[0]; cy = P[1]; cz = P[2];
  } else {
    const float* X0 = pts + (size_t)(b*3+0)*NPTS;
    const float* X1 = pts + (size_t)(b*3+1)*NPTS;
    const float* X2 = pts + (size_t)(b*3+2)*NPTS;
    #pragma unroll
    for (int t = 0; t < PL; ++t){
      int i = tid + 256*t;
      px[t] = X0[i]; py[t] = X1[i]; pz[t] = X2[i];
      sm.xS[i] = px[t]; sm.yS[i] = py[t]; sm.zS[i] = pz[t];
      d[t] = 1e10f;
    }
    cx = X0[0]; cy = X1[0]; cz = X2[0];
  }
  // pin the scan working set into VGPRs (non-rematerializable)
  #pragma unroll
  for (int t = 0; t < PL; ++t)
    asm volatile("" : "+v"(px[t]), "+v"(py[t]), "+v"(pz[t]), "+v"(d[t]));

  int far = 0;
  for (int s = 0; s < SS; ++s){
    if (tid == 0){
      sm.idxR[s] = far; sm.cxR[s] = cx; sm.cyR[s] = cy; sm.czR[s] = cz;
    }
    unsigned long long lkey;
    {
      float nd = fminf(d[0], dist3(px[0], py[0], pz[0], cx, cy, cz));
      d[0] = nd;
      lkey = ((unsigned long long)__float_as_uint(nd) << 32) | (~(unsigned)tid);
    }
    #pragma unroll
    for (int t = 1; t < PL; ++t){
      float nd = fminf(d[t], dist3(px[t], py[t], pz[t], cx, cy, cz));
      d[t] = nd;
      unsigned long long k = ((unsigned long long)__float_as_uint(nd) << 32)
                           | (~(unsigned)(tid + 256*t));
      if (k > lkey) lkey = k;
    }
    unsigned long long wkey = dpp_max_key(lkey);
    const int buf = s & 1;
    if (lane == 0) sm.keyS[buf][wid] = wkey;
    __syncthreads();
    unsigned long long gk = sm.keyS[buf][0];
    #pragma unroll
    for (int w = 1; w < 4; ++w){
      unsigned long long k = sm.keyS[buf][w];
      if (k > gk) gk = k;
    }
    far = (int)(~(unsigned)gk);
    cx = sm.xS[far]; cy = sm.yS[far]; cz = sm.zS[far];
  }
  __syncthreads();
  #pragma unroll
  for (int u = 0; u < ST; ++u){
    int s = u*256 + tid;
    idx_out[b*SS + s] = sm.idxR[s];
    newxyz[(b*SS+s)*3+0] = sm.cxR[s];
    newxyz[(b*SS+s)*3+1] = sm.cyR[s];
    newxyz[(b*SS+s)*3+2] = sm.czR[s];
  }
}

// ---------------------------------------------------------------------------
// kNN: one WAVE per center; DPP u64 min-reduce replaces the 6-step
// shfl_xor butterfly (6 dependent ds_bpermute ~780 cyc -> ~120 cyc VALU).
// key = dist_bits<<32 | idx: lexicographic min = min dist, tie -> min idx
// (identical selection rule to the verified butterfly version).
template<int NPTS>
__device__ __forceinline__ void dev_knn(const float* __restrict__ pts,
                                        const float* __restrict__ ctr,
                                        int S, int* __restrict__ knn,
                                        int gblk, int tid){
  constexpr int PL = NPTS/64;
  const int lane = tid & 63;
  const int g = gblk*4 + (tid >> 6);
  const int b = g / S;
  const float cx = ctr[g*3+0], cy = ctr[g*3+1], cz = ctr[g*3+2];
  const float* P = pts + (size_t)b*NPTS*3;
  float d[PL];
  #pragma unroll
  for (int t = 0; t < PL; ++t){
    int i = lane + 64*t;
    d[t] = dist3(cx, cy, cz, P[i*3+0], P[i*3+1], P[i*3+2]);
  }
  for (int k = 0; k < KG_; ++k){
    unsigned long long lkey = ((unsigned long long)__float_as_uint(d[0]) << 32)
                            | (unsigned)lane;
    #pragma unroll
    for (int t = 1; t < PL; ++t){
      unsigned long long kk = ((unsigned long long)__float_as_uint(d[t]) << 32)
                            | (unsigned)(lane + 64*t);
      if (kk < lkey) lkey = kk;
    }
    unsigned long long gk = dpp_min_key(lkey);
    int bi = (int)(unsigned)gk;
    if (lane == k) knn[g*KG_ + k] = bi;
    if ((bi & 63) == lane){
      const int wt = bi >> 6;
      #pragma unroll
      for (int t = 0; t < PL; ++t)
        if (t == wt) d[t] = 3.0e38f;
    }
  }
}

template<int NPTS>
__global__ __launch_bounds__(256) void knnw_k(const float* __restrict__ pts,
                                              const float* __restrict__ ctr,
                                              int S, int* __restrict__ knn){
  dev_knn<NPTS>(pts, ctr, S, knn, blockIdx.x, threadIdx.x);
}

// ---------------------------------------------------------------------------
// K1 = fps1 | transpose | stem1. Blocks: [0,32) fps1, [32,800) transpose,
// [800,1824) stem1.
union K1Smem {
  FpsSmemT<N1_, S1_> fps;
  float red[64][5];
};
__global__ __launch_bounds__(256) void k1_k(const float* __restrict__ x,
                                            int* __restrict__ idx1,
                                            float* __restrict__ nx1,
                                            float* __restrict__ xyzb,
                                            const float* __restrict__ w1,
                                            float* __restrict__ ssum,
                                            float* __restrict__ ssq){
  __shared__ K1Smem sm;
  const int blk = blockIdx.x, tid = threadIdx.x;
  if (blk < B_){
    dev_fps<N1_, S1_, false>(x, idx1, nx1, blk, sm.fps, tid);
  } else if (blk < B_ + 768){
    int e = (blk - B_)*256 + tid;           // < B*N*3
    int d = e % 3; int n = (e/3) % N1_; int b = e / (3*N1_);
    xyzb[e] = x[(b*3 + d)*N1_ + n];
  } else {
    const int c  = tid & 63;
    const int sl = tid >> 6;
    const float wx = w1[c*3+0], wy = w1[c*3+1], wz = w1[c*3+2];
    const int base = (blk - (B_+768))*64 + sl*16;
    float ls = 0.f, lq = 0.f;
    for (int r = 0; r < 16; ++r){
      int m = base + r;
      int b = m >> 11, n = m & 2047;
      float xv = x[(b*3+0)*N1_ + n];
      float yv = x[(b*3+1)*N1_ + n];
      float zv = x[(b*3+2)*N1_ + n];
      float h = xv*wx + yv*wy + zv*wz;
      ls += h; lq += h*h;
    }
    sm.red[c][sl] = ls; __syncthreads();
    if (sl == 0) atomicAdd(&ssum[c], sm.red[c][0]+sm.red[c][1]+sm.red[c][2]+sm.red[c][3]);
    __syncthreads();
    sm.red[c][sl] = lq; __syncthreads();
    if (sl == 0) atomicAdd(&ssq[c], sm.red[c][0]+sm.red[c][1]+sm.red[c][2]+sm.red[c][3]);
  }
}

// ---------------------------------------------------------------------------
// K2 = fps2 | knn1 | stem2. Blocks: [0,32) fps2, [32,4128) knn1, [4128,5152) stem2.
union K2Smem {
  FpsSmemT<S1_, S2_> fps;
  struct { float As[32][68]; float Ws[32][68]; float red[64][17]; } s2;
};
__global__ __launch_bounds__(256) void k2_k(const float* __restrict__ x,
                                            const float* __restrict__ xyzb,
                                            const float* __restrict__ nx1,
                                            int* __restrict__ idx2,
                                            float* __restrict__ nx2,
                                            int* __restrict__ knn1,
                                            const float* __restrict__ w1,
                                            const float* __restrict__ s0,
                                            const float* __restrict__ b0,
                                            const float* __restrict__ w2,
                                            float* __restrict__ hout,
                                            float* __restrict__ ssum,
                                            float* __restrict__ ssq){
  __shared__ K2Smem sm;
  const int blk = blockIdx.x, tid = threadIdx.x;
  if (blk < B_){
    dev_fps<S1_, S2_, true>(nx1, idx2, nx2, blk, sm.fps, tid);
  } else if (blk < B_ + 4096){
    dev_knn<N1_>(xyzb, nx1, S1_, knn1, blk - B_, tid);
  } else {
    const int m0 = (blk - (B_+4096)) * 64;
    const int lrow = tid >> 3;
    const int lk   = (tid & 7) * 4;
    const int tx = tid & 15, ty = tid >> 4;
    float acc[4][4];
    #pragma unroll
    for (int i=0;i<4;++i)
      #pragma unroll
      for (int j=0;j<4;++j) acc[i][j]=0.f;

    for (int k0 = 0; k0 < 64; k0 += 32){
      __syncthreads();
      #pragma unroll
      for (int p = 0; p < 2; ++p){
        int m = m0 + lrow + p*32;
        int b = m >> 11, n = m & 2047;
        float x0 = x[(b*3+0)*N1_ + n];
        float x1 = x[(b*3+1)*N1_ + n];
        float x2 = x[(b*3+2)*N1_ + n];
        #pragma unroll
        for (int j = 0; j < 4; ++j){
          int k = k0 + lk + j;
          float h = x0*w1[k*3+0] + x1*w1[k*3+1] + x2*w1[k*3+2];
          sm.s2.As[lk+j][lrow+p*32] = fmaxf(h*s0[k] + b0[k], 0.f);
        }
      }
      {
        const int cl = tid >> 2, kp = (tid & 3)*8;
        const float* wr = w2 + cl*64 + k0 + kp;
        #pragma unroll
        for (int q = 0; q < 2; ++q){
          float4 w = *reinterpret_cast<const float4*>(wr + q*4);
          sm.s2.Ws[kp+q*4+0][cl] = w.x; sm.s2.Ws[kp+q*4+1][cl] = w.y;
          sm.s2.Ws[kp+q*4+2][cl] = w.z; sm.s2.Ws[kp+q*4+3][cl] = w.w;
        }
      }
      __syncthreads();
      #pragma unroll
      for (int kk = 0; kk < 32; ++kk){
        float4 av = *reinterpret_cast<const float4*>(&sm.s2.As[kk][ty*4]);
        float4 wv = *reinterpret_cast<const float4*>(&sm.s2.Ws[kk][tx*4]);
        acc[0][0]+=av.x*wv.x; acc[0][1]+=av.x*wv.y; acc[0][2]+=av.x*wv.z; acc[0][3]+=av.x*wv.w;
        acc[1][0]+=av.y*wv.x; acc[1][1]+=av.y*wv.y; acc[1][2]+=av.y*wv.z; acc[1][3]+=av.y*wv.w;
        acc[2][0]+=av.z*wv.x; acc[2][1]+=av.z*wv.y; acc[2][2]+=av.z*wv.z; acc[2][3]+=av.z*wv.w;
        acc[3][0]+=av.w*wv.x; acc[3][1]+=av.w*wv.y; acc[3][2]+=av.w*wv.z; acc[3][3]+=av.w*wv.w;
      }
    }
    #pragma unroll
    for (int r = 0; r < 4; ++r){
      float4 o; o.x=acc[r][0]; o.y=acc[r][1]; o.z=acc[r][2]; o.w=acc[r][3];
      *reinterpret_cast<float4*>(hout + (size_t)(m0 + ty*4 + r)*64 + tx*4) = o;
    }
    __syncthreads();
    #pragma unroll
    for (int j = 0; j < 4; ++j)
      sm.s2.red[tx*4+j][ty] = acc[0][j]+acc[1][j]+acc[2][j]+acc[3][j];
    __syncthreads();
    if (tid < 64){
      float s = 0.f;
      #pragma unroll
      for (int t = 0; t < 16; ++t) s += sm.s2.red[tid][t];
      atomicAdd(&ssum[tid], s);
    }
    __syncthreads();
    #pragma unroll
    for (int j = 0; j < 4; ++j)
      sm.s2.red[tx*4+j][ty] = acc[0][j]*acc[0][j]+acc[1][j]*acc[1][j]
                            + acc[2][j]*acc[2][j]+acc[3][j]*acc[3][j];
    __syncthreads();
    if (tid < 64){
      float s = 0.f;
      #pragma unroll
      for (int t = 0; t < 16; ++t) s += sm.s2.red[tid][t];
      atomicAdd(&ssq[tid], s);
    }
  }
}

// ---------------------------------------------------------------------------
// pack fp32 weight rows into f16 B-fragment order
__global__ __launch_bounds__(256) void pack_w_k(const float* __restrict__ W,
                                                f16* __restrict__ out,
                                                int C, int Kfull, int koff,
                                                int total){
  int e = blockIdx.x*256 + threadIdx.x;
  if (e >= total) return;
  int lane = e & 63, tile = e >> 6;
  int ntiles = C/16;
  int nt = tile % ntiles, kt = tile / ntiles;
  int n = nt*16 + (lane & 15);
  int k0 = kt*32 + (lane >> 4)*8;
  const float* src = W + (size_t)n*Kfull + koff + k0;
  f16* dst = out + (size_t)e*8;
  #pragma unroll
  for (int j = 0; j < 8; ++j) dst[j] = (f16)src[j];
}

__global__ void finalize_bn_k(const float* __restrict__ ssum, const float* __restrict__ ssq,
                              const float* __restrict__ g,   const float* __restrict__ b,
                              float* __restrict__ scale, float* __restrict__ bias,
                              int C, float count){
  int c = threadIdx.x;
  if (c < C){
    double m = (double)ssum[c] / (double)count;
    double v = (double)ssq[c] / (double)count - m*m;
    if (v < 0.0) v = 0.0;
    float sc = g[c] * (float)(1.0 / sqrt(v + 1e-5));
    scale[c] = sc;
    bias[c]  = b[c] - (float)m * sc;
  }
}

__global__ __launch_bounds__(256) void bnrelu_k(const float* __restrict__ h,
                                                const float* __restrict__ sc,
                                                const float* __restrict__ bs,
                                                float* __restrict__ out, int total, int C){
  int e = blockIdx.x*256 + threadIdx.x;
  if (e < total){
    int c = e % C;
    out[e] = fmaxf(h[e]*sc[c] + bs[c], 0.f);
  }
}

__global__ __launch_bounds__(256) void gather_rows_k(const float* __restrict__ src,
                                                     const int* __restrict__ idx,
                                                     float* __restrict__ dst,
                                                     int total, int Dc, int Ssamp, int Npts){
  int e = blockIdx.x*256 + threadIdx.x;
  if (e < total){
    int g = e / Dc, c = e - g*Dc;
    int b = g / Ssamp;
    dst[e] = src[((size_t)(b*Npts + idx[g]))*Dc + c];
  }
}

// ---------------------------------------------------------------------------
// Fused SG-stage kernel, f16 MFMA. MAT=1: PASS0 stores raw h1 (f16) to h1g;
// PASS1 skips gather/staging/layer1 and loads h1 from h1g instead.
template<int DIN, int PASS, int MAT>
__global__ __launch_bounds__(256) void sgm_k(
    const float* __restrict__ f,   // [B*Npts, DIN]
    const float* __restrict__ cf,  // [B*S, DIN]
    const int* __restrict__ knn,
    const float* __restrict__ W1full,  // fp32 [C][2*DIN] (center half)
    const f16* __restrict__ W1p,       // packed rel half, K=DIN
    const f16* __restrict__ W2p,       // packed, K=C (PASS 1)
    const float* __restrict__ s1, const float* __restrict__ b1,
    float* __restrict__ ssum, float* __restrict__ ssq,
    float* __restrict__ gmx, float* __restrict__ gmn,
    f16* __restrict__ h1g,
    int Npts, int S)
{
  constexpr int C   = 2*DIN;
  constexpr int NT  = C/16;     // n-tiles
  constexpr int KT1 = DIN/32;   // k-tiles layer1
  constexpr int KT2 = C/32;     // k-tiles layer2
  constexpr int NTW = NT/4;     // n-tiles per wave
  constexpr int RP  = DIN + 8;  // rel row pitch (halfs)
  constexpr int HP  = C + 8;    // hT row pitch (halfs)

  __shared__ f16 relS[(PASS==1 && MAT==1) ? 8 : 32*RP];
  __shared__ float hcS[C];
  __shared__ float csS[DIN];
  __shared__ f16 hTS[PASS ? 32*HP : 8];

  const int tid = threadIdx.x;
  const int lane = tid & 63, wid = tid >> 6;
  const int col = lane & 15, quad = lane >> 4;

  float sAcc[NTW], qAcc[NTW];
  #pragma unroll
  for (int t = 0; t < NTW; ++t){ sAcc[t] = 0.f; qAcc[t] = 0.f; }

  for (int gi = 0; gi < GPB; ++gi){
    const int g = blockIdx.x*GPB + gi;
    const int b = g / S;
    __syncthreads();

    if (!(PASS == 1 && MAT == 1)){
      // ---- stage rel (f16) + center row ----
      {
        const int r = tid >> 3, part = tid & 7;
        const int j = knn[g*KG_ + r];
        const float* fr = f + (size_t)(b*Npts + j)*DIN + part*(DIN/8);
        const float* cr = cf + (size_t)g*DIN + part*(DIN/8);
        f16* dst = relS + r*RP + part*(DIN/8);
        #pragma unroll
        for (int q = 0; q < DIN/32; ++q){
          float4 fv = *reinterpret_cast<const float4*>(fr + q*4);
          float4 cv = *reinterpret_cast<const float4*>(cr + q*4);
          f16x4 hv;
          hv.x = (f16)(fv.x - cv.x); hv.y = (f16)(fv.y - cv.y);
          hv.z = (f16)(fv.z - cv.z); hv.w = (f16)(fv.w - cv.w);
          *reinterpret_cast<f16x4*>(dst + q*4) = hv;
        }
        if (tid < DIN) csS[tid] = cf[(size_t)g*DIN + tid];
      }
      __syncthreads();
      // ---- rank-1 center contribution (exact fp32) ----
      if (tid < C){
        const float* wr = W1full + (size_t)tid*C + DIN;
        float s = 0.f;
        for (int k = 0; k < DIN; k += 4){
          float4 w = *reinterpret_cast<const float4*>(wr + k);
          s += csS[k]*w.x + csS[k+1]*w.y + csS[k+2]*w.z + csS[k+3]*w.w;
        }
        hcS[tid] = s;
      }
      __syncthreads();
    }

    if (PASS == 0){
      // ---- layer1 A-frags ----
      f16x8 a1[2][KT1];
      #pragma unroll
      for (int mt = 0; mt < 2; ++mt)
        #pragma unroll
        for (int kt = 0; kt < KT1; ++kt)
          a1[mt][kt] = *reinterpret_cast<const f16x8*>(relS + (mt*16+col)*RP + kt*32 + quad*8);
      #pragma unroll
      for (int t = 0; t < NTW; ++t){
        const int nt = wid*NTW + t;
        const float hc = hcS[nt*16 + col];
        f32x4 acc0 = {hc,hc,hc,hc}, acc1 = {hc,hc,hc,hc};
        #pragma unroll
        for (int kt = 0; kt < KT1; ++kt){
          f16x8 bf = *reinterpret_cast<const f16x8*>(W1p + ((size_t)(kt*NT + nt)*64 + lane)*8);
          acc0 = __builtin_amdgcn_mfma_f32_16x16x32_f16(a1[0][kt], bf, acc0, 0, 0, 0);
          acc1 = __builtin_amdgcn_mfma_f32_16x16x32_f16(a1[1][kt], bf, acc1, 0, 0, 0);
        }
        float s = acc0[0]+acc0[1]+acc0[2]+acc0[3] + acc1[0]+acc1[1]+acc1[2]+acc1[3];
        float q = acc0[0]*acc0[0]+acc0[1]*acc0[1]+acc0[2]*acc0[2]+acc0[3]*acc0[3]
                + acc1[0]*acc1[0]+acc1[1]*acc1[1]+acc1[2]*acc1[2]+acc1[3]*acc1[3];
        s += __shfl_xor(s, 16); s += __shfl_xor(s, 32);
        q += __shfl_xor(q, 16); q += __shfl_xor(q, 32);
        sAcc[t] += s; qAcc[t] += q;
        if (MAT == 1){
          #pragma unroll
          for (int r = 0; r < 4; ++r){
            h1g[((size_t)g*32 + quad*4+r)*C + nt*16+col]    = (f16)acc0[r];
            h1g[((size_t)g*32 + 16+quad*4+r)*C + nt*16+col] = (f16)acc1[r];
          }
        }
      }
    } else {
      if (MAT == 1){
        // ---- load h1 from global, bnrelu -> hTS ----
        const int r = tid >> 3, part = tid & 7;
        const f16* src = h1g + ((size_t)g*32 + r)*C + part*(C/8);
        f16* dst = hTS + r*HP + part*(C/8);
        #pragma unroll
        for (int q = 0; q < C/32; ++q){
          f16x4 hv = *reinterpret_cast<const f16x4*>(src + q*4);
          float4 sc4 = *reinterpret_cast<const float4*>(s1 + part*(C/8) + q*4);
          float4 bs4 = *reinterpret_cast<const float4*>(b1 + part*(C/8) + q*4);
          f16x4 o;
          o.x = (f16)fmaxf((float)hv.x*sc4.x + bs4.x, 0.f);
          o.y = (f16)fmaxf((float)hv.y*sc4.y + bs4.y, 0.f);
          o.z = (f16)fmaxf((float)hv.z*sc4.z + bs4.z, 0.f);
          o.w = (f16)fmaxf((float)hv.w*sc4.w + bs4.w, 0.f);
          *reinterpret_cast<f16x4*>(dst + q*4) = o;
        }
      } else {
        // ---- recompute layer1, bnrelu -> hTS ----
        f16x8 a1[2][KT1];
        #pragma unroll
        for (int mt = 0; mt < 2; ++mt)
          #pragma unroll
          for (int kt = 0; kt < KT1; ++kt)
            a1[mt][kt] = *reinterpret_cast<const f16x8*>(relS + (mt*16+col)*RP + kt*32 + quad*8);
        #pragma unroll
        for (int t = 0; t < NTW; ++t){
          const int nt = wid*NTW + t;
          const float hc = hcS[nt*16 + col];
          f32x4 acc0 = {hc,hc,hc,hc}, acc1 = {hc,hc,hc,hc};
          #pragma unroll
          for (int kt = 0; kt < KT1; ++kt){
            f16x8 bf = *reinterpret_cast<const f16x8*>(W1p + ((size_t)(kt*NT + nt)*64 + lane)*8);
            acc0 = __builtin_amdgcn_mfma_f32_16x16x32_f16(a1[0][kt], bf, acc0, 0, 0, 0);
            acc1 = __builtin_amdgcn_mfma_f32_16x16x32_f16(a1[1][kt], bf, acc1, 0, 0, 0);
          }
          const float sc = s1[nt*16+col], bs = b1[nt*16+col];
          #pragma unroll
          for (int r = 0; r < 4; ++r){
            hTS[(quad*4+r)*HP + nt*16+col]    = (f16)fmaxf(acc0[r]*sc + bs, 0.f);
            hTS[(16+quad*4+r)*HP + nt*16+col] = (f16)fmaxf(acc1[r]*sc + bs, 0.f);
          }
        }
      }
      __syncthreads();   // hTS complete
      f16x8 a2[2][KT2];
      #pragma unroll
      for (int mt = 0; mt < 2; ++mt)
        #pragma unroll
        for (int kt = 0; kt < KT2; ++kt)
          a2[mt][kt] = *reinterpret_cast<const f16x8*>(hTS + (mt*16+col)*HP + kt*32 + quad*8);
      #pragma unroll
      for (int t = 0; t < NTW; ++t){
        const int nt = wid*NTW + t;
        f32x4 acc0 = {0.f,0.f,0.f,0.f}, acc1 = {0.f,0.f,0.f,0.f};
        #pragma unroll
        for (int kt = 0; kt < KT2; ++kt){
          f16x8 bf = *reinterpret_cast<const f16x8*>(W2p + ((size_t)(kt*NT + nt)*64 + lane)*8);
          acc0 = __builtin_amdgcn_mfma_f32_16x16x32_f16(a2[0][kt], bf, acc0, 0, 0, 0);
          acc1 = __builtin_amdgcn_mfma_f32_16x16x32_f16(a2[1][kt], bf, acc1, 0, 0, 0);
        }
        float s = acc0[0]+acc0[1]+acc0[2]+acc0[3] + acc1[0]+acc1[1]+acc1[2]+acc1[3];
        float q = acc0[0]*acc0[0]+acc0[1]*acc0[1]+acc0[2]*acc0[2]+acc0[3]*acc0[3]
                + acc1[0]*acc1[0]+acc1[1]*acc1[1]+acc1[2]*acc1[2]+acc1[3]*acc1[3];
        float mx = fmaxf(fmaxf(fmaxf(acc0[0],acc0[1]), fmaxf(acc0[2],acc0[3])),
                         fmaxf(fmaxf(acc1[0],acc1[1]), fmaxf(acc1[2],acc1[3])));
        float mn = fminf(fminf(fminf(acc0[0],acc0[1]), fminf(acc0[2],acc0[3])),
                         fminf(fminf(acc1[0],acc1[1]), fminf(acc1[2],acc1[3])));
        s += __shfl_xor(s, 16); s += __shfl_xor(s, 32);
        q += __shfl_xor(q, 16); q += __shfl_xor(q, 32);
        mx = fmaxf(mx, __shfl_xor(mx, 16)); mx = fmaxf(mx, __shfl_xor(mx, 32));
        mn = fminf(mn, __shfl_xor(mn, 16)); mn = fminf(mn, __shfl_xor(mn, 32));
        sAcc[t] += s; qAcc[t] += q;
        if (quad == 0){
          gmx[(size_t)g*C + nt*16 + col] = mx;
          gmn[(size_t)g*C + nt*16 + col] = mn;
        }
      }
    }
  } // group loop

  #pragma unroll
  for (int t = 0; t < NTW; ++t){
    const int nt = wid*NTW + t;
    if (quad == 0){
      atomicAdd(&ssum[nt*16 + col], sAcc[t]);
      atomicAdd(&ssq [nt*16 + col], qAcc[t]);
    }
  }
}

// combine: out[g][c] = relu(scale * (scale>=0 ? max : min) + bias)
__global__ __launch_bounds__(256) void combine_k(const float* __restrict__ mx,
                                                 const float* __restrict__ mn,
                                                 const float* __restrict__ sc,
                                                 const float* __restrict__ bs,
                                                 float* __restrict__ out, int total, int C){
  int e = blockIdx.x*256 + threadIdx.x;
  if (e < total){
    int c = e % C;
    float s = sc[c];
    float v = (s >= 0.f) ? mx[e] : mn[e];
    out[e] = fmaxf(s*v + bs[c], 0.f);
  }
}

// final: out[b][c][s] from group-major [b*S2+s][c]
__global__ __launch_bounds__(256) void final_out_k(const float* __restrict__ mx,
                                                   const float* __restrict__ mn,
                                                   const float* __restrict__ sc,
                                                   const float* __restrict__ bs,
                                                   float* __restrict__ out){
  int e = blockIdx.x*256 + threadIdx.x;     // < 32*256*256
  int s = e & 255;
  int c = (e >> 8) & 255;
  int b = e >> 16;
  int idx = ((b << 8) + s)*256 + c;
  float scv = sc[c];
  float v = (scv >= 0.f) ? mx[idx] : mn[idx];
  out[e] = fmaxf(scv*v + bs[c], 0.f);
}

// ---------------------------------------------------------------------------
extern "C" void kernel_launch(void* const* d_in, const int* in_sizes, int n_in,
                              void* d_out, int out_size, void* d_ws, size_t ws_size,
                              hipStream_t stream)
{
  const float* x      = (const float*)d_in[0];
  const float* w1     = (const float*)d_in[1];
  const float* g1     = (const float*)d_in[2];
  const float* b1     = (const float*)d_in[3];
  const float* w2     = (const float*)d_in[4];
  const float* g2     = (const float*)d_in[5];
  const float* b2     = (const float*)d_in[6];
  const float* sg1w1  = (const float*)d_in[7];
  const float* sg1g1  = (const float*)d_in[8];
  const float* sg1b1  = (const float*)d_in[9];
  const float* sg1w2  = (const float*)d_in[10];
  const float* sg1g2  = (const float*)d_in[11];
  const float* sg1b2  = (const float*)d_in[12];
  const float* sg2w1  = (const float*)d_in[13];
  const float* sg2g1  = (const float*)d_in[14];
  const float* sg2b1  = (const float*)d_in[15];
  const float* sg2w2  = (const float*)d_in[16];
  const float* sg2g2  = (const float*)d_in[17];
  const float* sg2b2  = (const float*)d_in[18];

  float* ws = (float*)d_ws;
  size_t off = 0;
  auto alloc = [&](size_t n){ float* p = ws + off; off += (n + 63) & ~(size_t)63; return p; };

  float* xyzb = alloc((size_t)B_*N1_*3);
  float* fbuf = alloc((size_t)B_*N1_*64);       // 16 MB
  float* f1   = alloc((size_t)B_*S1_*128);      // 8 MB
  float* cf   = alloc((size_t)B_*S1_*64);       // 4 MB
  float* nx1  = alloc((size_t)B_*S1_*3);
  float* nx2  = alloc((size_t)B_*S2_*3);
  float* stats= alloc(6*512);
  float* sb   = alloc(6*512);
  int* idx1   = (int*)alloc((size_t)B_*S1_);
  int* idx2   = (int*)alloc((size_t)B_*S2_);
  int* knn1   = (int*)alloc((size_t)B_*S1_*KG_);
  int* knn2   = (int*)alloc((size_t)B_*S2_*KG_);
  float* gmx  = alloc((size_t)B_*S1_*128);      // 8 MB
  float* gmn  = alloc((size_t)B_*S1_*128);      // 8 MB
  f16* w1p1 = (f16*)alloc(128*64/2);
  f16* w2p1 = (f16*)alloc(128*128/2);
  f16* w1p2 = (f16*)alloc(256*128/2);
  f16* w2p2 = (f16*)alloc(256*256/2);
  if (off * sizeof(float) > ws_size) return;

  // optional h1 materialization buffer (134 MB as f16); SG2 reuses it
  const size_t h1_halfs  = (size_t)B_*S1_*KG_*128;   // == B*S2*KG*256
  const bool   mat = ((off + h1_halfs/2) * sizeof(float) <= ws_size);
  f16* hbuf = mat ? (f16*)alloc(h1_halfs/2) : nullptr;

  float* st0 = stats + 0*512; float* st1 = stats + 1*512; float* st2 = stats + 2*512;
  float* st3 = stats + 3*512; float* st4 = stats + 4*512; float* st5 = stats + 5*512;
  float* sb0 = sb + 0*512; float* sb1 = sb + 1*512; float* sb2 = sb + 2*512;
  float* sb3 = sb + 3*512; float* sb4 = sb + 4*512; float* sb5 = sb + 5*512;

  (void)hipMemsetAsync(stats, 0, 6*512*sizeof(float), stream);

  // ---- pack weights to f16 B-fragment order ----
  pack_w_k<<<(2*8*64 +255)/256, 256, 0, stream>>>(sg1w1, w1p1, 128, 128, 0, 2*8*64);
  pack_w_k<<<(4*8*64 +255)/256, 256, 0, stream>>>(sg1w2, w2p1, 128, 128, 0, 4*8*64);
  pack_w_k<<<(4*16*64+255)/256, 256, 0, stream>>>(sg2w1, w1p2, 256, 256, 0, 4*16*64);
  pack_w_k<<<(8*16*64+255)/256, 256, 0, stream>>>(sg2w2, w2p2, 256, 256, 0, 8*16*64);

  // ---- K1 = fps1 | transpose | stem1 ----
  k1_k<<<B_ + 768 + 1024, 256, 0, stream>>>(x, idx1, nx1, xyzb, w1, st0, st0+256);
  finalize_bn_k<<<1, 256, 0, stream>>>(st0, st0+256, g1, b1, sb0, sb0+256, 64, 65536.f);

  // ---- K2 = fps2 | knn1 | stem2 ----
  k2_k<<<B_ + 4096 + 1024, 256, 0, stream>>>(x, xyzb, nx1, idx2, nx2, knn1,
      w1, sb0, sb0+256, w2, fbuf, st1, st1+256);
  finalize_bn_k<<<1, 256, 0, stream>>>(st1, st1+256, g2, b2, sb1, sb1+256, 64, 65536.f);
  bnrelu_k<<<(B_*N1_*64)/256, 256, 0, stream>>>(fbuf, sb1, sb1+256, fbuf, B_*N1_*64, 64);

  // ---- SG1 ----
  gather_rows_k<<<(B_*S1_*64)/256, 256, 0, stream>>>(fbuf, idx1, cf, B_*S1_*64, 64, S1_, N1_);
  if (mat){
    sgm_k<64,0,1><<<(B_*S1_)/GPB, 256, 0, stream>>>(fbuf, cf, knn1, sg1w1, w1p1, nullptr,
        nullptr, nullptr, st2, st2+256, nullptr, nullptr, hbuf, N1_, S1_);
  } else {
    sgm_k<64,0,0><<<(B_*S1_)/GPB, 256, 0, stream>>>(fbuf, cf, knn1, sg1w1, w1p1, nullptr,
        nullptr, nullptr, st2, st2+256, nullptr, nullptr, nullptr, N1_, S1_);
  }
  finalize_bn_k<<<1, 256, 0, stream>>>(st2, st2+256, sg1g1, sg1b1, sb2, sb2+256, 128, 524288.f);
  if (mat){
    sgm_k<64,1,1><<<(B_*S1_)/GPB, 256, 0, stream>>>(fbuf, cf, knn1, sg1w1, w1p1, w2p1,
        sb2, sb2+256, st3, st3+256, gmx, gmn, hbuf, N1_, S1_);
  } else {
    sgm_k<64,1,0><<<(B_*S1_)/GPB, 256, 0, stream>>>(fbuf, cf, knn1, sg1w1, w1p1, w2p1,
        sb2, sb2+256, st3, st3+256, gmx, gmn, nullptr, N1_, S1_);
  }
  finalize_bn_k<<<1, 256, 0, stream>>>(st3, st3+256, sg1g2, sg1b2, sb3, sb3+256, 128, 524288.f);
  combine_k<<<(B_*S1_*128)/256, 256, 0, stream>>>(gmx, gmn, sb3, sb3+256, f1, B_*S1_*128, 128);

  // ---- SG2 ----
  knnw_k<S1_><<<(B_*S2_)/4, 256, 0, stream>>>(nx1, nx2, S2_, knn2);
  gather_rows_k<<<(B_*S2_*128)/256, 256, 0, stream>>>(f1, idx2, cf, B_*S2_*128, 128, S2_, S1_);
  if (mat){
    sgm_k<128,0,1><<<(B_*S2_)/GPB, 256, 0, stream>>>(f1, cf, knn2, sg2w1, w1p2, nullptr,
        nullptr, nullptr, st4, st4+256, nullptr, nullptr, hbuf, S1_, S2_);
  } else {
    sgm_k<128,0,0><<<(B_*S2_)/GPB, 256, 0, stream>>>(f1, cf, knn2, sg2w1, w1p2, nullptr,
        nullptr, nullptr, st4, st4+256, nullptr, nullptr, nullptr, S1_, S2_);
  }
  finalize_bn_k<<<1, 256, 0, stream>>>(st4, st4+256, sg2g1, sg2b1, sb4, sb4+256, 256, 262144.f);
  if (mat){
    sgm_k<128,1,1><<<(B_*S2_)/GPB, 256, 0, stream>>>(f1, cf, knn2, sg2w1, w1p2, w2p2,
        sb4, sb4+256, st5, st5+256, gmx, gmn, hbuf, S1_, S2_);
  } else {
    sgm_k<128,1,0><<<(B_*S2_)/GPB, 256, 0, stream>>>(f1, cf, knn2, sg2w1, w1p2, w2p2,
        sb4, sb4+256, st5, st5+256, gmx, gmn, nullptr, S1_, S2_);
  }
  finalize_bn_k<<<1, 256, 0, stream>>>(st5, st5+256, sg2g2, sg2b2, sb5, sb5+256, 256, 262144.f);
  final_out_k<<<(B_*256*S2_)/256, 256, 0, stream>>>(gmx, gmn, sb5, sb5+256, (float*)d_out);
}